// Round 10
// baseline (220.363 us; speedup 1.0000x reference)
//
#include <hip/hip_runtime.h>
#include <stdint.h>

typedef float f32x4 __attribute__((ext_vector_type(4)));
typedef short bf16x8 __attribute__((ext_vector_type(8)));

__device__ __forceinline__ float bf2f(unsigned short h){
  union { unsigned int u; float f; } v; v.u = ((unsigned int)h) << 16; return v.f;
}
__device__ __forceinline__ unsigned short f2bf(float f){
  union { float f; unsigned int u; } v; v.f = f;
  return (unsigned short)((v.u + 0x7fffu + ((v.u >> 16) & 1u)) >> 16);
}

typedef __attribute__((address_space(1))) const unsigned int ga_u32;
typedef __attribute__((address_space(3))) unsigned int ls_u32;
__device__ __forceinline__ void async_load16(const void* g, void* l){
  __builtin_amdgcn_global_load_lds((ga_u32*)g, (ls_u32*)l, 16, 0, 0);
}

#define CFENCE() asm volatile("" ::: "memory")

// ---------------------------------------------------------------------------
// unified prep: weights->bf16 (5x512x512), biases->packed, wq1x2 dup (from fp32)
__global__ __launch_bounds__(256) void k_prep_all(
    const float* __restrict__ w0, const float* __restrict__ w1,
    const float* __restrict__ w2, const float* __restrict__ w3,
    const float* __restrict__ w4,
    const float* __restrict__ b0, const float* __restrict__ b1,
    const float* __restrict__ b2, const float* __restrict__ b3,
    const float* __restrict__ b4,
    unsigned short* __restrict__ wbf, float* __restrict__ bias5,
    unsigned short* __restrict__ wq1x2)
{
  const int bid = blockIdx.x;
  const int t = threadIdx.x;
  if (bid < 5120){
    int slot = bid >> 10;
    int i = (bid & 1023) * 256 + t;
    const float* w = (slot == 0) ? w0 : (slot == 1) ? w1 :
                     (slot == 2) ? w2 : (slot == 3) ? w3 : w4;
    wbf[(size_t)slot * 262144 + i] = f2bf(w[i]);
  } else if (bid < 5130){
    int i = (bid - 5120) * 256 + t;   // 0..2559
    int s = i >> 9, r = i & 511;
    const float* b = (s == 0) ? b0 : (s == 1) ? b1 : (s == 2) ? b2 :
                     (s == 3) ? b3 : b4;
    bias5[i] = b[r];
  } else {
    int e = bid - 5130;               // 0..511
    #pragma unroll
    for (int rep = 0; rep < 2; rep++){
      int idx = rep*256 + t;
      unsigned short v = f2bf(w3[e*512 + idx]);   // w3 == Wq1 fp32
      wq1x2[(size_t)e*1024 + idx] = v;
      wq1x2[(size_t)e*1024 + 512 + idx] = v;
    }
  }
}

// ---------------------------------------------------------------------------
// build xs_bf[b][l][c], xsT[b][c][l], svec[b][c] partial col-sums.
__global__ __launch_bounds__(256) void k_build_xs(
    const float* __restrict__ x, const float* __restrict__ pos,
    unsigned short* __restrict__ xsb, unsigned short* __restrict__ xsT,
    float* __restrict__ svec)
{
  __shared__ float tile[64][65];
  __shared__ unsigned short tile2[64][72];
  __shared__ float sred[256];
  const int lt = blockIdx.x, ct = blockIdx.y;
  const int t = threadIdx.x;
  const int rr = t >> 3, c8 = (t & 7) * 8;
  float pr[16];
  #pragma unroll
  for (int pass = 0; pass < 2; pass++){
    int gl = lt*64 + rr + pass*32;
    f32x4 p0 = *(const f32x4*)(pos + (size_t)gl * 512 + ct*64 + c8);
    f32x4 p1 = *(const f32x4*)(pos + (size_t)gl * 512 + ct*64 + c8 + 4);
    #pragma unroll
    for (int s = 0; s < 4; s++){ pr[pass*8+s] = p0[s]; pr[pass*8+4+s] = p1[s]; }
  }
  for (int b = 0; b < 8; b++){
    #pragma unroll
    for (int pass = 0; pass < 2; pass++){
      int r = rr + pass * 32;
      const float* src = x + ((size_t)b * 512 + ct*64 + r) * 4096 + lt*64 + c8;
      f32x4 v0 = *(const f32x4*)src;
      f32x4 v1 = *(const f32x4*)(src + 4);
      #pragma unroll
      for (int s = 0; s < 4; s++){ tile[r][c8+s] = v0[s]; tile[r][c8+4+s] = v1[s]; }
    }
    __syncthreads();
    #pragma unroll
    for (int pass = 0; pass < 2; pass++){
      int ll = rr + pass * 32;
      int gl = lt*64 + ll;
      bf16x8 hv;
      #pragma unroll
      for (int s = 0; s < 8; s++){
        unsigned short h = f2bf(tile[c8+s][ll] + pr[pass*8+s]);
        hv[s] = (short)h;
        tile2[c8+s][ll] = h;
      }
      *(bf16x8*)(xsb + ((size_t)b * 4096 + gl) * 512 + ct*64 + c8) = hv;
    }
    __syncthreads();
    #pragma unroll
    for (int rep = 0; rep < 2; rep++){
      int c = rep*32 + (t >> 3);
      int l0 = (t & 7) * 8;
      bf16x8 v = *(const bf16x8*)&tile2[c][l0];
      *(bf16x8*)(xsT + ((size_t)b * 512 + ct*64 + c) * 4096 + lt*64 + l0) = v;
    }
    {
      const int c = t & 63, lq = t >> 6;
      float s_ = 0.f;
      #pragma unroll
      for (int j = 0; j < 16; j++) s_ += bf2f(tile2[c][lq*16 + j]);
      sred[t] = s_;
      __syncthreads();
      if (t < 64){
        float ss = sred[t] + sred[t+64] + sred[t+128] + sred[t+192];
        atomicAdd(&svec[b*512 + ct*64 + t], ss);
      }
    }
    __syncthreads();
  }
}

// ---------------------------------------------------------------------------
// row softmax: S[row][0..511] fp32 -> mid bf16
__global__ __launch_bounds__(64) void k_softmax(
    const float* __restrict__ S, unsigned short* __restrict__ mid)
{
  const size_t row = blockIdx.x;
  const int lane = threadIdx.x;
  const float* p = S + row * 512 + lane * 8;
  f32x4 v0 = *(const f32x4*)p, v1 = *(const f32x4*)(p + 4);
  float mx = v0[0];
  #pragma unroll
  for (int s = 1; s < 4; s++) mx = fmaxf(mx, v0[s]);
  #pragma unroll
  for (int s = 0; s < 4; s++) mx = fmaxf(mx, v1[s]);
  #pragma unroll
  for (int m = 1; m < 64; m <<= 1) mx = fmaxf(mx, __shfl_xor(mx, m));
  float e[8]; float sum = 0.f;
  #pragma unroll
  for (int s = 0; s < 4; s++){ e[s]   = __expf(v0[s] - mx); sum += e[s]; }
  #pragma unroll
  for (int s = 0; s < 4; s++){ e[4+s] = __expf(v1[s] - mx); sum += e[4+s]; }
  #pragma unroll
  for (int m = 1; m < 64; m <<= 1) sum += __shfl_xor(sum, m);
  float inv = 1.0f / sum;
  bf16x8 hv;
  #pragma unroll
  for (int s = 0; s < 8; s++) hv[s] = (short)f2bf(e[s] * inv);
  *(bf16x8*)(mid + row * 512 + lane * 8) = hv;
}

// ---------------------------------------------------------------------------
// mid transpose with diag fold: midT[z][d][c] = mid[z][c][d] * diag[z][c]
__global__ __launch_bounds__(256) void k_transpose_scale(
    const unsigned short* __restrict__ in, const float* __restrict__ diag,
    unsigned short* __restrict__ out)
{
  __shared__ float tile[64][65];
  const int rt = blockIdx.x, ct = blockIdx.y, z = blockIdx.z;
  const unsigned short* src = in  + (size_t)z * 262144;
  unsigned short*       dst = out + (size_t)z * 262144;
  const int t = threadIdx.x;
  const int rr = t >> 3, c8 = (t & 7) * 8;
  #pragma unroll
  for (int pass = 0; pass < 2; pass++){
    int r = rr + pass * 32;
    bf16x8 v = *(const bf16x8*)(src + (size_t)(rt*64 + r) * 512 + ct*64 + c8);
    #pragma unroll
    for (int s = 0; s < 8; s++) tile[r][c8+s] = bf2f((unsigned short)v[s]);
  }
  __syncthreads();
  f32x4 dg0 = *(const f32x4*)(diag + z*512 + rt*64 + c8);
  f32x4 dg1 = *(const f32x4*)(diag + z*512 + rt*64 + c8 + 4);
  #pragma unroll
  for (int pass = 0; pass < 2; pass++){
    int c = rr + pass * 32;
    bf16x8 hv;
    #pragma unroll
    for (int s = 0; s < 4; s++) hv[s]   = (short)f2bf(tile[c8+s][c]   * dg0[s]);
    #pragma unroll
    for (int s = 0; s < 4; s++) hv[4+s] = (short)f2bf(tile[c8+4+s][c] * dg1[s]);
    *(bf16x8*)(dst + (size_t)(ct*64 + c) * 512 + rt*64 + c8) = hv;
  }
}

// ===========================================================================
// 128x128-tile 2-phase GEMM machinery (64KB LDS -> 2 blocks/CU).
// ===========================================================================
#define GEMM_PRE()                                                            \
  const int tid = threadIdx.x;                                                \
  const int lane = tid & 63;                                                  \
  const int wave = tid >> 6;                                                  \
  const int wm = wave >> 1, wn = wave & 1;                                    \
  size_t aoff[4], boff[4]; int ldsq[4];                                       \
  _Pragma("unroll")                                                           \
  for (int i = 0; i < 4; i++){                                                \
    int qq = i*4 + wave;                                                      \
    int ch = qq*64 + lane;                                                    \
    int m  = ch >> 3, p = ch & 7;                                             \
    int lc = p ^ (m & 7);                                                     \
    aoff[i] = (size_t)(m0 + m) * K + lc*8;                                    \
    boff[i] = (size_t)m * K + lc*8;                                           \
    ldsq[i] = qq * 1024;                                                      \
  }                                                                           \
  f32x4 acc[4][4];                                                            \
  const f32x4 vzero = {0.f,0.f,0.f,0.f};                                      \
  _Pragma("unroll")                                                           \
  for (int i = 0; i < 4; i++)                                                 \
    _Pragma("unroll")                                                         \
    for (int j = 0; j < 4; j++) acc[i][j] = vzero;                            \
  int arow[4], brow[4];                                                       \
  _Pragma("unroll")                                                           \
  for (int f = 0; f < 4; f++){                                                \
    arow[f] = (wm*64 + f*16 + (lane & 15)) * 64;                              \
    brow[f] = (wn*64 + f*16 + (lane & 15)) * 64;                              \
  }                                                                           \
  const int kg = lane >> 4;                                                   \
  const int l7 = lane & 7;                                                    \
  const int l15 = lane & 15;

#define GEMM_STAGE2(buf, kt, BB)                                              \
  _Pragma("unroll")                                                           \
  for (int i = 0; i < 4; i++){                                                \
    async_load16(Ae + aoff[i] + (kt)*64, (char*)&smem[(buf)*8192] + ldsq[i]); \
    async_load16((BB) + boff[i] + (kt)*64, (char*)&smem[16384 + (buf)*8192] + ldsq[i]); \
  }

#define GEMM_COMPUTE2(buf, ACC)                                               \
  _Pragma("unroll")                                                           \
  for (int ks = 0; ks < 2; ks++){                                             \
    bf16x8 a[4], b[4];                                                        \
    const int pa = (ks*4 + kg) ^ l7;                                          \
    _Pragma("unroll")                                                         \
    for (int f = 0; f < 4; f++){                                              \
      a[f] = *(const bf16x8*)&smem[(buf)*8192 + arow[f] + pa*8];              \
      b[f] = *(const bf16x8*)&smem[16384 + (buf)*8192 + brow[f] + pa*8];      \
    }                                                                         \
    _Pragma("unroll")                                                         \
    for (int i = 0; i < 4; i++)                                               \
      _Pragma("unroll")                                                       \
      for (int j = 0; j < 4; j++)                                             \
        (ACC)[i][j] = __builtin_amdgcn_mfma_f32_16x16x32_bf16(a[i], b[j], (ACC)[i][j], 0, 0, 0); \
  }

#define GEMM_KLOOP2(nkt, BB)                                                  \
  GEMM_STAGE2(0, 0, BB);                                                      \
  __syncthreads();                                                            \
  { int cur = 0;                                                              \
    for (int kt = 0; kt < (nkt); kt++){                                       \
      if (kt + 1 < (nkt)) { GEMM_STAGE2(cur ^ 1, kt + 1, BB); }               \
      GEMM_COMPUTE2(cur, acc);                                                \
      __syncthreads();                                                        \
      cur ^= 1;                                                               \
    } }

// ===========================================================================
// MEGA kernel: proj (Q + chained KV) + G-syrk + uw, one launch.
// grid = 2320 = 8 XCD-chunks x 290 (32 G + 256 proj + 2 uw).
// ===========================================================================
__global__ __launch_bounds__(256, 2) void k_mega(
    const unsigned short* __restrict__ A,      // xsb
    const unsigned short* __restrict__ xsT,
    const unsigned short* __restrict__ W,
    const float* __restrict__ bias5,
    const float* __restrict__ svec,
    unsigned short* __restrict__ Qb,
    unsigned short* __restrict__ Gstk,
    float* __restrict__ diag, float* __restrict__ ksum,
    float* __restrict__ uvec, float* __restrict__ wvec)
{
  __shared__ unsigned short smem[32768];   // 64KB
  const int bid = blockIdx.x;
  const int xcd = bid & 7, local = bid >> 3;   // local 0..289

  if (local < 32){
    // ---------------- G-syrk path ----------------
    const int gw = xcd*32 + local;               // 0..255
    const int part = gw & 1;
    const int ntile = (gw >> 1) & 3;
    const int mtile = (gw >> 3) & 3;
    const int z = gw >> 5;
    const int m0 = mtile * 128, n0 = ntile * 128;
    const int K = 4096;
    const unsigned short* Ae = xsT + (size_t)z * 2097152 + part * 2048;
    const unsigned short* Be = Ae + (size_t)n0 * 4096;

    GEMM_PRE();
    GEMM_KLOOP2(32, Be);

    #pragma unroll
    for (int j = 0; j < 4; j++){
      const int cl = wn*64 + j*16 + l15;
      #pragma unroll
      for (int i = 0; i < 4; i++){
        const int rb = wm*64 + i*16 + kg*4;
        #pragma unroll
        for (int q = 0; q < 4; q++)
          smem[(rb + q)*136 + cl] = f2bf(acc[i][j][q]);
      }
    }
    __syncthreads();
    #pragma unroll
    for (int rep = 0; rep < 8; rep++){
      const int rl = rep*16 + (tid >> 4);
      const int c0 = (tid & 15) * 8;
      bf16x8 v = *(const bf16x8*)&smem[rl*136 + c0];
      *(bf16x8*)(Gstk + (size_t)z*524288 + (size_t)(m0 + rl)*1024 + part*512 + n0 + c0) = v;
    }
    return;
  }

  if (local >= 288){
    // ---------------- uw path ----------------
    const int uwid = xcd*2 + (local - 288);      // 0..15
    const int sel = uwid & 1, b = uwid >> 1;
    const int t = threadIdx.x;
    float* sv = (float*)(void*)smem;             // 2KB
    sv[t] = svec[b*512 + t]; sv[t+256] = svec[b*512 + t + 256];
    __syncthreads();
    const unsigned short* Wp = W + (size_t)(3 + sel) * 262144;
    float* o = sel ? wvec : uvec;
    #pragma unroll
    for (int rep = 0; rep < 2; rep++){
      int e = rep*256 + t;
      const unsigned short* row = Wp + (size_t)e * 512;
      float acc_ = 0.f;
      for (int ch = 0; ch < 64; ch++){
        bf16x8 v = *(const bf16x8*)(row + ch*8);
        #pragma unroll
        for (int j = 0; j < 8; j++) acc_ += bf2f((unsigned short)v[j]) * sv[ch*8+j];
      }
      o[b*512 + e] = acc_;
    }
    return;
  }

  // ---------------- proj path ----------------
  const int pw = xcd*256 + (local - 32);         // 0..2047
  const int mtile = pw >> 3;                     // 0..255
  const int unit  = pw & 7;
  const int m0 = mtile * 128;
  const int K = 512;
  const unsigned short* Ae = A;

  int mode, cb;
  const unsigned short* BeK; const unsigned short* BeV = W;
  if (unit < 4){ mode = 0; cb = unit*128;     BeK = W + (size_t)cb * 512; }
  else         { mode = 1; cb = (unit-4)*128; BeK = W + 262144 + (size_t)cb * 512;
                                              BeV = W + 524288 + (size_t)cb * 512; }

  GEMM_PRE();

  if (mode == 1){
    const int bz = mtile >> 5;
    GEMM_STAGE2(0, 0, BeK);
    __syncthreads();
    int cur = 0;
    for (int kt = 0; kt < 8; kt++){
      if (kt < 7) { GEMM_STAGE2(cur ^ 1, kt + 1, BeK); }
      else        { GEMM_STAGE2(cur ^ 1, 0, BeV); }
      GEMM_COMPUTE2(cur, acc);
      __syncthreads();
      cur ^= 1;
    }
    GEMM_STAGE2(cur ^ 1, 1, BeV);
    unsigned int kpk[4][4][2];
    #pragma unroll
    for (int j = 0; j < 4; j++){
      const int cj = cb + wn*64 + j*16 + l15;
      const float bb = bias5[512 + cj];
      float ks_ = 0.f;
      #pragma unroll
      for (int i = 0; i < 4; i++){
        #pragma unroll
        for (int h = 0; h < 2; h++){
          float v0 = acc[i][j][2*h]   + bb; v0 = v0 > 0.f ? v0 : 0.f;
          float v1 = acc[i][j][2*h+1] + bb; v1 = v1 > 0.f ? v1 : 0.f;
          unsigned short h0 = f2bf(v0), h1 = f2bf(v1);
          kpk[i][j][h] = (unsigned)h0 | ((unsigned)h1 << 16);
          ks_ += bf2f(h0) + bf2f(h1);
        }
        acc[i][j] = vzero;
      }
      ks_ += __shfl_xor(ks_, 16);
      ks_ += __shfl_xor(ks_, 32);
      if (lane < 16) atomicAdd(&ksum[bz*512 + cj], ks_);
    }
    for (int kt = 0; kt < 8; kt++){
      if (kt >= 1 && kt < 7) { GEMM_STAGE2(cur ^ 1, kt + 1, BeV); }
      GEMM_COMPUTE2(cur, acc);
      __syncthreads();
      cur ^= 1;
    }
    #pragma unroll
    for (int j = 0; j < 4; j++){
      const int cj = cb + wn*64 + j*16 + l15;
      const float bb = bias5[1024 + cj];
      float dv = 0.f;
      #pragma unroll
      for (int i = 0; i < 4; i++){
        #pragma unroll
        for (int h = 0; h < 2; h++){
          float v0 = bf2f(f2bf(acc[i][j][2*h]   + bb));
          float v1 = bf2f(f2bf(acc[i][j][2*h+1] + bb));
          dv += bf2f((unsigned short)(kpk[i][j][h] & 0xffffu)) * v0
              + bf2f((unsigned short)(kpk[i][j][h] >> 16))     * v1;
        }
      }
      dv += __shfl_xor(dv, 16);
      dv += __shfl_xor(dv, 32);
      if (lane < 16) atomicAdd(&diag[bz*512 + cj], dv);
    }
    return;
  }

  GEMM_KLOOP2(8, BeK);

  #pragma unroll
  for (int j = 0; j < 4; j++){
    const int cl = wn*64 + j*16 + l15;
    const float bb = bias5[cb + cl];
    #pragma unroll
    for (int i = 0; i < 4; i++){
      const int rb = wm*64 + i*16 + kg*4;
      #pragma unroll
      for (int q = 0; q < 4; q++){
        float v = acc[i][j][q] + bb; v = v > 0.f ? v : 0.f;
        smem[(rb + q)*136 + cl] = f2bf(v);
      }
    }
  }
  __syncthreads();
  #pragma unroll
  for (int rep = 0; rep < 8; rep++){
    const int rl = rep*16 + (tid >> 4);
    const int c0 = (tid & 15) * 8;
    bf16x8 v = *(const bf16x8*)&smem[rl*136 + c0];
    *(bf16x8*)(Qb + (size_t)(m0 + rl) * 512 + cb + c0) = v;
  }
}

// ===========================================================================
// k_pz: gemm_P (bids 0..127) co-launched with k_z (bids 128..8319).
// Both depend only on mega outputs; mutually independent.
// ===========================================================================
__global__ __launch_bounds__(256) void k_pz(
    const unsigned short* __restrict__ Wq1x2,
    const unsigned short* __restrict__ Gstk,
    unsigned short* __restrict__ P,
    const unsigned short* __restrict__ Qb,
    const float* __restrict__ ksum,
    float* __restrict__ Z)
{
  __shared__ unsigned short smem[32768];
  const int bid = blockIdx.x;

  if (bid >= 128){
    // ---------------- Z path ----------------
    const int row = (bid - 128) * 4 + ((int)threadIdx.x >> 6);
    const int lane = threadIdx.x & 63;
    const int b = row >> 12;
    bf16x8 q = *(const bf16x8*)(Qb + (size_t)row * 512 + lane * 8);
    f32x4 k0 = *(const f32x4*)(ksum + b*512 + lane*8);
    f32x4 k1 = *(const f32x4*)(ksum + b*512 + lane*8 + 4);
    float den = 0.f;
    #pragma unroll
    for (int s = 0; s < 4; s++) den += bf2f((unsigned short)q[s])   * (k0[s] + 1e-6f);
    #pragma unroll
    for (int s = 0; s < 4; s++) den += bf2f((unsigned short)q[4+s]) * (k1[s] + 1e-6f);
    #pragma unroll
    for (int m = 1; m < 64; m <<= 1) den += __shfl_xor(den, m);
    if (lane == 0) Z[row] = 1.0f / den;
    return;
  }

  // ---------------- P path: P[z] = Wq1 @ (G0+G1), K=1024 ----------------
  const int wgid = (bid & 7) * 16 + (bid >> 3);    // bijective on 0..127
  const int z = wgid >> 4;
  const int mtile = (wgid >> 2) & 3, ntile = wgid & 3;
  const int m0 = mtile * 128, n0 = ntile * 128;
  const int K = 1024;
  const unsigned short* Ae = Wq1x2;
  const unsigned short* Be = Gstk + (size_t)z * 524288 + (size_t)n0 * 1024;

  GEMM_PRE();
  GEMM_KLOOP2(16, Be);

  #pragma unroll
  for (int j = 0; j < 4; j++){
    const int cl = wn*64 + j*16 + l15;
    #pragma unroll
    for (int i = 0; i < 4; i++){
      const int rb = wm*64 + i*16 + kg*4;
      #pragma unroll
      for (int q = 0; q < 4; q++)
        smem[(rb + q)*136 + cl] = f2bf(acc[i][j][q]);
    }
  }
  __syncthreads();
  #pragma unroll
  for (int rep = 0; rep < 8; rep++){
    const int rl = rep*16 + (tid >> 4);
    const int c0 = (tid & 15) * 8;
    bf16x8 v = *(const bf16x8*)&smem[rl*136 + c0];
    *(bf16x8*)(P + (size_t)z * 262144 + (size_t)(m0 + rl) * 512 + n0 + c0) = v;
  }
}

// ---------------------------------------------------------------------------
// S[z] = P[z] @ Wk1^T + u bk1^T + bq1 w^T + L bq1 bk1^T  (fp32 out)
__global__ __launch_bounds__(256) void gemm_S(
    const unsigned short* __restrict__ P,
    const unsigned short* __restrict__ Wk1b,
    const float* __restrict__ bias5,
    const float* __restrict__ u, const float* __restrict__ w,
    float* __restrict__ Sf)
{
  __shared__ unsigned short smem[32768];
  const int bid = blockIdx.x;
  const int wgid = (bid & 7) * 16 + (bid >> 3);    // 128 blocks
  const int z = wgid >> 4;
  const int mtile = (wgid >> 2) & 3, ntile = wgid & 3;
  const int m0 = mtile * 128, n0 = ntile * 128;
  const int K = 512;
  const unsigned short* Ae = P + (size_t)z * 262144;
  const unsigned short* Be = Wk1b + (size_t)n0 * 512;

  GEMM_PRE();
  GEMM_KLOOP2(8, Be);

  #pragma unroll
  for (int j = 0; j < 4; j++){
    int cd = n0 + wn*64 + j*16 + l15;
    float bkv = bias5[2048 + cd];
    float wv  = w[z*512 + cd] + 4096.0f * bkv;
    #pragma unroll
    for (int i = 0; i < 4; i++){
      int r = m0 + wm*64 + i*16 + kg*4;
      #pragma unroll
      for (int q = 0; q < 4; q++){
        int rr = r + q;
        float uq  = u[z*512 + rr];
        float bqv = bias5[1536 + rr];
        Sf[(size_t)z * 262144 + (size_t)rr * 512 + cd] =
            acc[i][j][q] + uq * bkv + bqv * wv;
      }
    }
  }
}

// ===========================================================================
// result GEMM (128² 2-phase, 1024 blocks, 2/CU):
// y = xs + gamma*Z[l]*(Q @ midT'^T) in-place + BN stats.
// ===========================================================================
__global__ __launch_bounds__(256, 2) void gemm_res2(
    const unsigned short* __restrict__ A,        // Qb [32768][512]
    const unsigned short* __restrict__ Bt,       // midT' [8][512][512]
    const float* __restrict__ Zp,                // [32768]
    unsigned short* __restrict__ outh,           // xs bf16, in-place -> y
    const float* __restrict__ gamma_p,
    float* __restrict__ bnS, float* __restrict__ bnQ)
{
  __shared__ unsigned short smem[32768];
  __shared__ float zbuf[128];
  const int bid = blockIdx.x;
  const int wgid = (bid & 7) * 128 + (bid >> 3);   // 1024 % 8 == 0: bijective
  const int mtile = wgid >> 2;                     // 0..255
  const int ntile = wgid & 3;
  const int m0 = mtile * 128;
  const int nc0 = ntile * 128;
  const int K = 512;
  const unsigned short* Ae = A;
  const unsigned short* Be =
      Bt + (size_t)(mtile >> 5) * 262144 + (size_t)nc0 * 512;

  GEMM_PRE();
  GEMM_KLOOP2(8, Be);

  const float g = gamma_p[0];
  if (tid < 128) zbuf[tid] = Zp[m0 + tid];
  __syncthreads();
  // stage 1: g*Z*acc -> LDS bf16 (stride 136, conflict-free)
  #pragma unroll
  for (int j = 0; j < 4; j++){
    const int cl = wn*64 + j*16 + l15;
    #pragma unroll
    for (int i = 0; i < 4; i++){
      const int rb = wm*64 + i*16 + kg*4;
      #pragma unroll
      for (int q = 0; q < 4; q++){
        const int rl = rb + q;
        smem[rl*136 + cl] = f2bf(g * zbuf[rl] * acc[i][j][q]);
      }
    }
  }
  __syncthreads();
  // stage 2: coalesced RMW over the 128x128 tile + per-thread col partials
  float sc[8] = {0.f,0.f,0.f,0.f,0.f,0.f,0.f,0.f};
  float sq[8] = {0.f,0.f,0.f,0.f,0.f,0.f,0.f,0.f};
  const int c0 = (tid & 15) * 8;
  #pragma unroll
  for (int rep = 0; rep < 8; rep++){
    const int rl = rep*16 + (tid >> 4);
    bf16x8 ga = *(const bf16x8*)&smem[rl*136 + c0];
    size_t gidx = (size_t)(m0 + rl) * 512 + nc0 + c0;
    bf16x8 xv = *(const bf16x8*)(outh + gidx);
    bf16x8 yv;
    #pragma unroll
    for (int j = 0; j < 8; j++){
      float y = bf2f((unsigned short)xv[j]) + bf2f((unsigned short)ga[j]);
      yv[j] = (short)f2bf(y);
      sc[j] += y; sq[j] += y * y;
    }
    *(bf16x8*)(outh + gidx) = yv;
  }
  __syncthreads();
  // stage 3: reduce col partials across the 16 row-groups, then atomics
  float* red = (float*)(void*)smem;     // [16][128] sc ; +2048: [16][128] sq
  const int tg = tid >> 4;
  f32x4 s0 = {sc[0],sc[1],sc[2],sc[3]}, s1 = {sc[4],sc[5],sc[6],sc[7]};
  f32x4 q0 = {sq[0],sq[1],sq[2],sq[3]}, q1 = {sq[4],sq[5],sq[6],sq[7]};
  *(f32x4*)&red[tg*128 + c0]        = s0;  *(f32x4*)&red[tg*128 + c0 + 4]        = s1;
  *(f32x4*)&red[2048 + tg*128 + c0] = q0;  *(f32x4*)&red[2048 + tg*128 + c0 + 4] = q1;
  __syncthreads();
  if (tid < 128){
    float ss = 0.f, qq = 0.f;
    #pragma unroll
    for (int gg = 0; gg < 16; gg++){
      ss += red[gg*128 + tid];
      qq += red[2048 + gg*128 + tid];
    }
    atomicAdd(&bnS[nc0 + tid], ss);
    atomicAdd(&bnQ[nc0 + tid], qq);
  }
}

// ---------------------------------------------------------------------------
// finalize: y[b][l][c] bf16 -> out[b][c][l] fp32, BN affine + relu
__global__ __launch_bounds__(256) void k_bn_finalize(
    const unsigned short* __restrict__ y, const float* __restrict__ bnS,
    const float* __restrict__ bnQ, const float* __restrict__ bnw,
    const float* __restrict__ bnb, float* __restrict__ out)
{
  __shared__ float tile[64][65];
  __shared__ float scale_s[64], shift_s[64];
  const int lt = blockIdx.x, ct = blockIdx.y, b = blockIdx.z;
  const int t = threadIdx.x;
  if (t < 64){
    int c = ct*64 + t;
    float s = bnS[c], q = bnQ[c];
    float mean = s * (1.0f / 32768.0f);
    float var  = q * (1.0f / 32768.0f) - mean * mean;
    float inv  = rsqrtf(var + 1e-5f);
    float scv  = bnw[c] * inv;
    scale_s[t] = scv;
    shift_s[t] = bnb[c] - mean * scv;
  }
  const int rr = t >> 3, c8 = (t & 7) * 8;
  #pragma unroll
  for (int pass = 0; pass < 2; pass++){
    int l = rr + pass * 32;
    bf16x8 v = *(const bf16x8*)(y + ((size_t)b * 4096 + lt*64 + l) * 512 + ct*64 + c8);
    #pragma unroll
    for (int s = 0; s < 8; s++) tile[l][c8+s] = bf2f((unsigned short)v[s]);
  }
  __syncthreads();
  #pragma unroll
  for (int pass = 0; pass < 2; pass++){
    int c = rr + pass * 32;
    float scv = scale_s[c], sh = shift_s[c];
    f32x4 o0, o1;
    #pragma unroll
    for (int s = 0; s < 4; s++){
      float v = tile[c8+s][c] * scv + sh;     o0[s] = v > 0.f ? v : 0.f;
      float w = tile[c8+4+s][c] * scv + sh;   o1[s] = w > 0.f ? w : 0.f;
    }
    float* dp = out + ((size_t)b * 512 + ct*64 + c) * 4096 + lt*64 + c8;
    *(f32x4*)dp = o0;
    *(f32x4*)(dp + 4) = o1;
  }
}

// ---------------------------------------------------------------------------
extern "C" void kernel_launch(void* const* d_in, const int* in_sizes, int n_in,
                              void* d_out, int out_size, void* d_ws, size_t ws_size,
                              hipStream_t stream)
{
  const float* x    = (const float*)d_in[0];
  const float* pos  = (const float*)d_in[1];
  const float* Wq   = (const float*)d_in[2];
  const float* bq   = (const float*)d_in[3];
  const float* Wk   = (const float*)d_in[4];
  const float* bk   = (const float*)d_in[5];
  const float* Wv   = (const float*)d_in[6];
  const float* bv   = (const float*)d_in[7];
  const float* Wq1  = (const float*)d_in[8];
  const float* bq1  = (const float*)d_in[9];
  const float* Wk1  = (const float*)d_in[10];
  const float* bk1  = (const float*)d_in[11];
  const float* gam  = (const float*)d_in[12];
  const float* bnw  = (const float*)d_in[13];
  const float* bnb  = (const float*)d_in[14];
  float* out = (float*)d_out;
  char* ws = (char*)d_ws;

  const size_t MB = 1ull << 20;
  const size_t OFF_XSB  = 0;                  // 32MB xs_bf -> y in-place
  const size_t OFF_QB   = 32*MB;              // 32MB Q
  const size_t OFF_XST  = 64*MB;              // 32MB xs^T [8][512][4096]
  const size_t OFF_GSTK = 96*MB;              // 8MB  Gstack bf16 [8][512][1024]
  const size_t OFF_PBF  = 104*MB;             // 4MB  P bf16
  const size_t OFF_SF   = 108*MB;             // 8MB  S fp32
  const size_t OFF_MIDB = 116*MB;             // 4MB  mid bf16
  const size_t OFF_MIDT = 120*MB;             // 4MB  midT' bf16 (diag-scaled)
  const size_t OFF_WBF  = 124*MB;             // 2.5MB
  const size_t OFF_WQ2  = 127*MB;             // 1MB  Wq1 duplicated [512][1024]
  const size_t OFF_B5   = 128*MB + 512*1024;  // 10KB
  const size_t OFF_UV   = 129*MB;             // 16KB u
  const size_t OFF_WV   = OFF_UV + 16384;     // 16KB w
  const size_t OFF_Z    = OFF_WV + 16384;     // 128KB Z fp32
  const size_t OFF_DIAG = 130*MB;             // zeroed region start
  const size_t OFF_KSUM = OFF_DIAG + 16384;
  const size_t OFF_BNS  = OFF_KSUM + 16384;
  const size_t OFF_BNQ  = OFF_BNS + 2048;
  const size_t OFF_SV   = OFF_BNQ + 2048;
  const size_t ZERO_LEN = 16384 + 16384 + 2048 + 2048 + 16384;
  const size_t WS_NEED  = OFF_SV + 16384;
  if (ws_size < WS_NEED) return;

  unsigned short* xsb  = (unsigned short*)(ws + OFF_XSB);
  unsigned short* Qb   = (unsigned short*)(ws + OFF_QB);
  unsigned short* xsT  = (unsigned short*)(ws + OFF_XST);
  unsigned short* Gstk = (unsigned short*)(ws + OFF_GSTK);
  unsigned short* Pbf  = (unsigned short*)(ws + OFF_PBF);
  float*          Sf   = (float*)(ws + OFF_SF);
  unsigned short* midb = (unsigned short*)(ws + OFF_MIDB);
  unsigned short* midT = (unsigned short*)(ws + OFF_MIDT);
  unsigned short* wbf  = (unsigned short*)(ws + OFF_WBF);
  unsigned short* wq1x2= (unsigned short*)(ws + OFF_WQ2);
  float* bias5 = (float*)(ws + OFF_B5);
  float* uvec = (float*)(ws + OFF_UV);
  float* wvec = (float*)(ws + OFF_WV);
  float* Zp   = (float*)(ws + OFF_Z);
  float* diag = (float*)(ws + OFF_DIAG);
  float* ksum = (float*)(ws + OFF_KSUM);
  float* bnS  = (float*)(ws + OFF_BNS);
  float* bnQ  = (float*)(ws + OFF_BNQ);
  float* svec = (float*)(ws + OFF_SV);

  hipMemsetAsync(ws + OFF_DIAG, 0, ZERO_LEN, stream);

  // unified prep (weights bf16, biases, wq1x2 straight from fp32 Wq1)
  k_prep_all<<<dim3(5642), 256, 0, stream>>>(Wq, Wk, Wv, Wq1, Wk1,
                                             bq, bk, bv, bq1, bk1,
                                             wbf, bias5, wq1x2);

  // xs, xs^T, and column-sums in one pass (pos read once)
  k_build_xs<<<dim3(64, 8), 256, 0, stream>>>(x, pos, xsb, xsT, svec);

  // MEGA: proj (Q + chained-KV) + G-syrk + uw co-scheduled in one launch
  k_mega<<<dim3(2320), 256, 0, stream>>>(xsb, xsT, wbf, bias5, svec,
                                         Qb, Gstk, diag, ksum, uvec, wvec);

  // gemm_P co-launched with Z row-normalizer (independent paths)
  k_pz<<<dim3(8320), 256, 0, stream>>>(wq1x2, Gstk, Pbf, Qb, ksum, Zp);

  // S = Wq1 G Wk1^T + rank-1 corrections
  gemm_S<<<dim3(128), 256, 0, stream>>>(Pbf, wbf + 4*262144, bias5, uvec, wvec, Sf);

  k_softmax<<<dim3(4096), 64, 0, stream>>>(Sf, midb);
  k_transpose_scale<<<dim3(8, 8, 8), 256, 0, stream>>>(midb, diag, midT);

  // result GEMM (128², 2/CU) + residual + BN-stat epilogue (y in-place)
  gemm_res2<<<dim3(1024), 256, 0, stream>>>(Qb, midT, Zp, xsb, gam, bnS, bnQ);

  k_bn_finalize<<<dim3(64, 8, 8), 256, 0, stream>>>(xsb, bnS, bnQ, bnw, bnb, out);
}

// Round 11
// 215.623 us; speedup vs baseline: 1.0220x; 1.0220x over previous
//
#include <hip/hip_runtime.h>
#include <stdint.h>

typedef float f32x4 __attribute__((ext_vector_type(4)));
typedef short bf16x8 __attribute__((ext_vector_type(8)));

__device__ __forceinline__ float bf2f(unsigned short h){
  union { unsigned int u; float f; } v; v.u = ((unsigned int)h) << 16; return v.f;
}
__device__ __forceinline__ unsigned short f2bf(float f){
  union { float f; unsigned int u; } v; v.f = f;
  return (unsigned short)((v.u + 0x7fffu + ((v.u >> 16) & 1u)) >> 16);
}

typedef __attribute__((address_space(1))) const unsigned int ga_u32;
typedef __attribute__((address_space(3))) unsigned int ls_u32;
__device__ __forceinline__ void async_load16(const void* g, void* l){
  __builtin_amdgcn_global_load_lds((ga_u32*)g, (ls_u32*)l, 16, 0, 0);
}

#define CFENCE() asm volatile("" ::: "memory")

// ===========================================================================
// merged prep + build_xs:
//  bid 0..511    : build xs/xsT/svec (lt = bid&63, ct = bid>>6)  [heavy, first]
//  bid 512..5631 : weights fp32->bf16 (5 x 512x512)
//  bid 5632..5641: biases packed
//  bid 5642..6153: wq1x2 dup from fp32 Wq1
// ===========================================================================
__global__ __launch_bounds__(256) void k_prep_build(
    const float* __restrict__ x, const float* __restrict__ pos,
    const float* __restrict__ w0, const float* __restrict__ w1,
    const float* __restrict__ w2, const float* __restrict__ w3,
    const float* __restrict__ w4,
    const float* __restrict__ b0, const float* __restrict__ b1,
    const float* __restrict__ b2, const float* __restrict__ b3,
    const float* __restrict__ b4,
    unsigned short* __restrict__ xsb, unsigned short* __restrict__ xsT,
    float* __restrict__ svec,
    unsigned short* __restrict__ wbf, float* __restrict__ bias5,
    unsigned short* __restrict__ wq1x2)
{
  __shared__ float tile[64][65];
  __shared__ unsigned short tile2[64][72];
  __shared__ float sred[256];
  const int bid = blockIdx.x;
  const int t = threadIdx.x;

  if (bid >= 512){
    if (bid < 5632){
      int wbid = bid - 512;
      int slot = wbid >> 10;
      int i = (wbid & 1023) * 256 + t;
      const float* w = (slot == 0) ? w0 : (slot == 1) ? w1 :
                       (slot == 2) ? w2 : (slot == 3) ? w3 : w4;
      wbf[(size_t)slot * 262144 + i] = f2bf(w[i]);
    } else if (bid < 5642){
      int i = (bid - 5632) * 256 + t;   // 0..2559
      int s = i >> 9, r = i & 511;
      const float* b = (s == 0) ? b0 : (s == 1) ? b1 : (s == 2) ? b2 :
                       (s == 3) ? b3 : b4;
      bias5[i] = b[r];
    } else {
      int e = bid - 5642;               // 0..511
      #pragma unroll
      for (int rep = 0; rep < 2; rep++){
        int idx = rep*256 + t;
        unsigned short v = f2bf(w3[e*512 + idx]);   // w3 == Wq1 fp32
        wq1x2[(size_t)e*1024 + idx] = v;
        wq1x2[(size_t)e*1024 + 512 + idx] = v;
      }
    }
    return;
  }

  // ---------------- build path ----------------
  const int lt = bid & 63, ct = bid >> 6;
  const int rr = t >> 3, c8 = (t & 7) * 8;
  float pr[16];
  #pragma unroll
  for (int pass = 0; pass < 2; pass++){
    int gl = lt*64 + rr + pass*32;
    f32x4 p0 = *(const f32x4*)(pos + (size_t)gl * 512 + ct*64 + c8);
    f32x4 p1 = *(const f32x4*)(pos + (size_t)gl * 512 + ct*64 + c8 + 4);
    #pragma unroll
    for (int s = 0; s < 4; s++){ pr[pass*8+s] = p0[s]; pr[pass*8+4+s] = p1[s]; }
  }
  for (int b = 0; b < 8; b++){
    #pragma unroll
    for (int pass = 0; pass < 2; pass++){
      int r = rr + pass * 32;
      const float* src = x + ((size_t)b * 512 + ct*64 + r) * 4096 + lt*64 + c8;
      f32x4 v0 = *(const f32x4*)src;
      f32x4 v1 = *(const f32x4*)(src + 4);
      #pragma unroll
      for (int s = 0; s < 4; s++){ tile[r][c8+s] = v0[s]; tile[r][c8+4+s] = v1[s]; }
    }
    __syncthreads();
    #pragma unroll
    for (int pass = 0; pass < 2; pass++){
      int ll = rr + pass * 32;
      int gl = lt*64 + ll;
      bf16x8 hv;
      #pragma unroll
      for (int s = 0; s < 8; s++){
        unsigned short h = f2bf(tile[c8+s][ll] + pr[pass*8+s]);
        hv[s] = (short)h;
        tile2[c8+s][ll] = h;
      }
      *(bf16x8*)(xsb + ((size_t)b * 4096 + gl) * 512 + ct*64 + c8) = hv;
    }
    __syncthreads();
    #pragma unroll
    for (int rep = 0; rep < 2; rep++){
      int c = rep*32 + (t >> 3);
      int l0 = (t & 7) * 8;
      bf16x8 v = *(const bf16x8*)&tile2[c][l0];
      *(bf16x8*)(xsT + ((size_t)b * 512 + ct*64 + c) * 4096 + lt*64 + l0) = v;
    }
    {
      const int c = t & 63, lq = t >> 6;
      float s_ = 0.f;
      #pragma unroll
      for (int j = 0; j < 16; j++) s_ += bf2f(tile2[c][lq*16 + j]);
      sred[t] = s_;
      __syncthreads();
      if (t < 64){
        float ss = sred[t] + sred[t+64] + sred[t+128] + sred[t+192];
        atomicAdd(&svec[b*512 + ct*64 + t], ss);
      }
    }
    __syncthreads();
  }
}

// ===========================================================================
// merged softmax + diag-scale + transpose:
// midT[z][d][c] = softmax_d(S[z][c][:])[d] * diag[z][c]
// grid (64 rowchunks, 8 z), 256 threads; 8 rows per block, wave-parallel.
// ===========================================================================
__global__ __launch_bounds__(256) void k_softmax_t2(
    const float* __restrict__ Sf, const float* __restrict__ diag,
    unsigned short* __restrict__ midT)
{
  __shared__ unsigned short tr[8][520];
  const int rc = blockIdx.x, z = blockIdx.y;
  const int t = threadIdx.x;
  const int w = t >> 6, lane = t & 63;
  #pragma unroll
  for (int rr = 0; rr < 2; rr++){
    int cl = w*2 + rr;                     // 0..7
    int c = rc*8 + cl;
    const float* p = Sf + ((size_t)z*512 + c)*512 + lane*8;
    f32x4 v0 = *(const f32x4*)p, v1 = *(const f32x4*)(p + 4);
    float mx = v0[0];
    #pragma unroll
    for (int s = 1; s < 4; s++) mx = fmaxf(mx, v0[s]);
    #pragma unroll
    for (int s = 0; s < 4; s++) mx = fmaxf(mx, v1[s]);
    #pragma unroll
    for (int m = 1; m < 64; m <<= 1) mx = fmaxf(mx, __shfl_xor(mx, m));
    float e[8]; float sum = 0.f;
    #pragma unroll
    for (int s = 0; s < 4; s++){ e[s]   = __expf(v0[s] - mx); sum += e[s]; }
    #pragma unroll
    for (int s = 0; s < 4; s++){ e[4+s] = __expf(v1[s] - mx); sum += e[4+s]; }
    #pragma unroll
    for (int m = 1; m < 64; m <<= 1) sum += __shfl_xor(sum, m);
    float scl = diag[z*512 + c] / sum;
    #pragma unroll
    for (int s = 0; s < 8; s++) tr[cl][lane*8 + s] = f2bf(e[s] * scl);
  }
  __syncthreads();
  #pragma unroll
  for (int rep = 0; rep < 2; rep++){
    int d = rep*256 + t;
    bf16x8 hv;
    #pragma unroll
    for (int s = 0; s < 8; s++) hv[s] = (short)tr[s][d];
    *(bf16x8*)(midT + ((size_t)z*512 + d)*512 + rc*8) = hv;
  }
}

// ===========================================================================
// 128x128-tile 2-phase GEMM machinery (64KB LDS -> 2 blocks/CU).
// ===========================================================================
#define GEMM_PRE()                                                            \
  const int tid = threadIdx.x;                                                \
  const int lane = tid & 63;                                                  \
  const int wave = tid >> 6;                                                  \
  const int wm = wave >> 1, wn = wave & 1;                                    \
  size_t aoff[4], boff[4]; int ldsq[4];                                       \
  _Pragma("unroll")                                                           \
  for (int i = 0; i < 4; i++){                                                \
    int qq = i*4 + wave;                                                      \
    int ch = qq*64 + lane;                                                    \
    int m  = ch >> 3, p = ch & 7;                                             \
    int lc = p ^ (m & 7);                                                     \
    aoff[i] = (size_t)(m0 + m) * K + lc*8;                                    \
    boff[i] = (size_t)m * K + lc*8;                                           \
    ldsq[i] = qq * 1024;                                                      \
  }                                                                           \
  f32x4 acc[4][4];                                                            \
  const f32x4 vzero = {0.f,0.f,0.f,0.f};                                      \
  _Pragma("unroll")                                                           \
  for (int i = 0; i < 4; i++)                                                 \
    _Pragma("unroll")                                                         \
    for (int j = 0; j < 4; j++) acc[i][j] = vzero;                            \
  int arow[4], brow[4];                                                       \
  _Pragma("unroll")                                                           \
  for (int f = 0; f < 4; f++){                                                \
    arow[f] = (wm*64 + f*16 + (lane & 15)) * 64;                              \
    brow[f] = (wn*64 + f*16 + (lane & 15)) * 64;                              \
  }                                                                           \
  const int kg = lane >> 4;                                                   \
  const int l7 = lane & 7;                                                    \
  const int l15 = lane & 15;

#define GEMM_STAGE2(buf, kt, BB)                                              \
  _Pragma("unroll")                                                           \
  for (int i = 0; i < 4; i++){                                                \
    async_load16(Ae + aoff[i] + (kt)*64, (char*)&smem[(buf)*8192] + ldsq[i]); \
    async_load16((BB) + boff[i] + (kt)*64, (char*)&smem[16384 + (buf)*8192] + ldsq[i]); \
  }

#define GEMM_COMPUTE2(buf, ACC)                                               \
  _Pragma("unroll")                                                           \
  for (int ks = 0; ks < 2; ks++){                                             \
    bf16x8 a[4], b[4];                                                        \
    const int pa = (ks*4 + kg) ^ l7;                                          \
    _Pragma("unroll")                                                         \
    for (int f = 0; f < 4; f++){                                              \
      a[f] = *(const bf16x8*)&smem[(buf)*8192 + arow[f] + pa*8];              \
      b[f] = *(const bf16x8*)&smem[16384 + (buf)*8192 + brow[f] + pa*8];      \
    }                                                                         \
    _Pragma("unroll")                                                         \
    for (int i = 0; i < 4; i++)                                               \
      _Pragma("unroll")                                                       \
      for (int j = 0; j < 4; j++)                                             \
        (ACC)[i][j] = __builtin_amdgcn_mfma_f32_16x16x32_bf16(a[i], b[j], (ACC)[i][j], 0, 0, 0); \
  }

#define GEMM_KLOOP2(nkt, BB)                                                  \
  GEMM_STAGE2(0, 0, BB);                                                      \
  __syncthreads();                                                            \
  { int cur = 0;                                                              \
    for (int kt = 0; kt < (nkt); kt++){                                       \
      if (kt + 1 < (nkt)) { GEMM_STAGE2(cur ^ 1, kt + 1, BB); }               \
      GEMM_COMPUTE2(cur, acc);                                                \
      __syncthreads();                                                        \
      cur ^= 1;                                                               \
    } }

// ===========================================================================
// MEGA kernel: proj (Q + chained KV) + G-syrk + uw, one launch.
// grid = 2320 = 8 XCD-chunks x 290 (32 G + 256 proj + 2 uw).
// ===========================================================================
__global__ __launch_bounds__(256, 2) void k_mega(
    const unsigned short* __restrict__ A,      // xsb
    const unsigned short* __restrict__ xsT,
    const unsigned short* __restrict__ W,
    const float* __restrict__ bias5,
    const float* __restrict__ svec,
    unsigned short* __restrict__ Qb,
    unsigned short* __restrict__ Gstk,
    float* __restrict__ diag, float* __restrict__ ksum,
    float* __restrict__ uvec, float* __restrict__ wvec)
{
  __shared__ unsigned short smem[32768];   // 64KB
  const int bid = blockIdx.x;
  const int xcd = bid & 7, local = bid >> 3;   // local 0..289

  if (local < 32){
    // ---------------- G-syrk path ----------------
    const int gw = xcd*32 + local;               // 0..255
    const int part = gw & 1;
    const int ntile = (gw >> 1) & 3;
    const int mtile = (gw >> 3) & 3;
    const int z = gw >> 5;
    const int m0 = mtile * 128, n0 = ntile * 128;
    const int K = 4096;
    const unsigned short* Ae = xsT + (size_t)z * 2097152 + part * 2048;
    const unsigned short* Be = Ae + (size_t)n0 * 4096;

    GEMM_PRE();
    GEMM_KLOOP2(32, Be);

    #pragma unroll
    for (int j = 0; j < 4; j++){
      const int cl = wn*64 + j*16 + l15;
      #pragma unroll
      for (int i = 0; i < 4; i++){
        const int rb = wm*64 + i*16 + kg*4;
        #pragma unroll
        for (int q = 0; q < 4; q++)
          smem[(rb + q)*136 + cl] = f2bf(acc[i][j][q]);
      }
    }
    __syncthreads();
    #pragma unroll
    for (int rep = 0; rep < 8; rep++){
      const int rl = rep*16 + (tid >> 4);
      const int c0 = (tid & 15) * 8;
      bf16x8 v = *(const bf16x8*)&smem[rl*136 + c0];
      *(bf16x8*)(Gstk + (size_t)z*524288 + (size_t)(m0 + rl)*1024 + part*512 + n0 + c0) = v;
    }
    return;
  }

  if (local >= 288){
    // ---------------- uw path ----------------
    const int uwid = xcd*2 + (local - 288);      // 0..15
    const int sel = uwid & 1, b = uwid >> 1;
    const int t = threadIdx.x;
    float* sv = (float*)(void*)smem;             // 2KB
    sv[t] = svec[b*512 + t]; sv[t+256] = svec[b*512 + t + 256];
    __syncthreads();
    const unsigned short* Wp = W + (size_t)(3 + sel) * 262144;
    float* o = sel ? wvec : uvec;
    #pragma unroll
    for (int rep = 0; rep < 2; rep++){
      int e = rep*256 + t;
      const unsigned short* row = Wp + (size_t)e * 512;
      float acc_ = 0.f;
      for (int ch = 0; ch < 64; ch++){
        bf16x8 v = *(const bf16x8*)(row + ch*8);
        #pragma unroll
        for (int j = 0; j < 8; j++) acc_ += bf2f((unsigned short)v[j]) * sv[ch*8+j];
      }
      o[b*512 + e] = acc_;
    }
    return;
  }

  // ---------------- proj path ----------------
  const int pw = xcd*256 + (local - 32);         // 0..2047
  const int mtile = pw >> 3;                     // 0..255
  const int unit  = pw & 7;
  const int m0 = mtile * 128;
  const int K = 512;
  const unsigned short* Ae = A;

  int mode, cb;
  const unsigned short* BeK; const unsigned short* BeV = W;
  if (unit < 4){ mode = 0; cb = unit*128;     BeK = W + (size_t)cb * 512; }
  else         { mode = 1; cb = (unit-4)*128; BeK = W + 262144 + (size_t)cb * 512;
                                              BeV = W + 524288 + (size_t)cb * 512; }

  GEMM_PRE();

  if (mode == 1){
    const int bz = mtile >> 5;
    GEMM_STAGE2(0, 0, BeK);
    __syncthreads();
    int cur = 0;
    for (int kt = 0; kt < 8; kt++){
      if (kt < 7) { GEMM_STAGE2(cur ^ 1, kt + 1, BeK); }
      else        { GEMM_STAGE2(cur ^ 1, 0, BeV); }
      GEMM_COMPUTE2(cur, acc);
      __syncthreads();
      cur ^= 1;
    }
    GEMM_STAGE2(cur ^ 1, 1, BeV);
    unsigned int kpk[4][4][2];
    #pragma unroll
    for (int j = 0; j < 4; j++){
      const int cj = cb + wn*64 + j*16 + l15;
      const float bb = bias5[512 + cj];
      float ks_ = 0.f;
      #pragma unroll
      for (int i = 0; i < 4; i++){
        #pragma unroll
        for (int h = 0; h < 2; h++){
          float v0 = acc[i][j][2*h]   + bb; v0 = v0 > 0.f ? v0 : 0.f;
          float v1 = acc[i][j][2*h+1] + bb; v1 = v1 > 0.f ? v1 : 0.f;
          unsigned short h0 = f2bf(v0), h1 = f2bf(v1);
          kpk[i][j][h] = (unsigned)h0 | ((unsigned)h1 << 16);
          ks_ += bf2f(h0) + bf2f(h1);
        }
        acc[i][j] = vzero;
      }
      ks_ += __shfl_xor(ks_, 16);
      ks_ += __shfl_xor(ks_, 32);
      if (lane < 16) atomicAdd(&ksum[bz*512 + cj], ks_);
    }
    for (int kt = 0; kt < 8; kt++){
      if (kt >= 1 && kt < 7) { GEMM_STAGE2(cur ^ 1, kt + 1, BeV); }
      GEMM_COMPUTE2(cur, acc);
      __syncthreads();
      cur ^= 1;
    }
    #pragma unroll
    for (int j = 0; j < 4; j++){
      const int cj = cb + wn*64 + j*16 + l15;
      const float bb = bias5[1024 + cj];
      float dv = 0.f;
      #pragma unroll
      for (int i = 0; i < 4; i++){
        #pragma unroll
        for (int h = 0; h < 2; h++){
          float v0 = bf2f(f2bf(acc[i][j][2*h]   + bb));
          float v1 = bf2f(f2bf(acc[i][j][2*h+1] + bb));
          dv += bf2f((unsigned short)(kpk[i][j][h] & 0xffffu)) * v0
              + bf2f((unsigned short)(kpk[i][j][h] >> 16))     * v1;
        }
      }
      dv += __shfl_xor(dv, 16);
      dv += __shfl_xor(dv, 32);
      if (lane < 16) atomicAdd(&diag[bz*512 + cj], dv);
    }
    return;
  }

  GEMM_KLOOP2(8, BeK);

  #pragma unroll
  for (int j = 0; j < 4; j++){
    const int cl = wn*64 + j*16 + l15;
    const float bb = bias5[cb + cl];
    #pragma unroll
    for (int i = 0; i < 4; i++){
      const int rb = wm*64 + i*16 + kg*4;
      #pragma unroll
      for (int q = 0; q < 4; q++){
        float v = acc[i][j][q] + bb; v = v > 0.f ? v : 0.f;
        smem[(rb + q)*136 + cl] = f2bf(v);
      }
    }
  }
  __syncthreads();
  #pragma unroll
  for (int rep = 0; rep < 8; rep++){
    const int rl = rep*16 + (tid >> 4);
    const int c0 = (tid & 15) * 8;
    bf16x8 v = *(const bf16x8*)&smem[rl*136 + c0];
    *(bf16x8*)(Qb + (size_t)(m0 + rl) * 512 + cb + c0) = v;
  }
}

// ===========================================================================
// k_pz: gemm_P (bids 0..127) co-launched with k_z (bids 128..8319).
// ===========================================================================
__global__ __launch_bounds__(256) void k_pz(
    const unsigned short* __restrict__ Wq1x2,
    const unsigned short* __restrict__ Gstk,
    unsigned short* __restrict__ P,
    const unsigned short* __restrict__ Qb,
    const float* __restrict__ ksum,
    float* __restrict__ Z)
{
  __shared__ unsigned short smem[32768];
  const int bid = blockIdx.x;

  if (bid >= 128){
    // ---------------- Z path ----------------
    const int row = (bid - 128) * 4 + ((int)threadIdx.x >> 6);
    const int lane = threadIdx.x & 63;
    const int b = row >> 12;
    bf16x8 q = *(const bf16x8*)(Qb + (size_t)row * 512 + lane * 8);
    f32x4 k0 = *(const f32x4*)(ksum + b*512 + lane*8);
    f32x4 k1 = *(const f32x4*)(ksum + b*512 + lane*8 + 4);
    float den = 0.f;
    #pragma unroll
    for (int s = 0; s < 4; s++) den += bf2f((unsigned short)q[s])   * (k0[s] + 1e-6f);
    #pragma unroll
    for (int s = 0; s < 4; s++) den += bf2f((unsigned short)q[4+s]) * (k1[s] + 1e-6f);
    #pragma unroll
    for (int m = 1; m < 64; m <<= 1) den += __shfl_xor(den, m);
    if (lane == 0) Z[row] = 1.0f / den;
    return;
  }

  // ---------------- P path: P[z] = Wq1 @ (G0+G1), K=1024 ----------------
  const int wgid = (bid & 7) * 16 + (bid >> 3);    // bijective on 0..127
  const int z = wgid >> 4;
  const int mtile = (wgid >> 2) & 3, ntile = wgid & 3;
  const int m0 = mtile * 128, n0 = ntile * 128;
  const int K = 1024;
  const unsigned short* Ae = Wq1x2;
  const unsigned short* Be = Gstk + (size_t)z * 524288 + (size_t)n0 * 1024;

  GEMM_PRE();
  GEMM_KLOOP2(16, Be);

  #pragma unroll
  for (int j = 0; j < 4; j++){
    const int cl = wn*64 + j*16 + l15;
    #pragma unroll
    for (int i = 0; i < 4; i++){
      const int rb = wm*64 + i*16 + kg*4;
      #pragma unroll
      for (int q = 0; q < 4; q++)
        smem[(rb + q)*136 + cl] = f2bf(acc[i][j][q]);
    }
  }
  __syncthreads();
  #pragma unroll
  for (int rep = 0; rep < 8; rep++){
    const int rl = rep*16 + (tid >> 4);
    const int c0 = (tid & 15) * 8;
    bf16x8 v = *(const bf16x8*)&smem[rl*136 + c0];
    *(bf16x8*)(P + (size_t)z * 262144 + (size_t)(m0 + rl) * 512 + n0 + c0) = v;
  }
}

// ---------------------------------------------------------------------------
// S[z] = P[z] @ Wk1^T + u bk1^T + bq1 w^T + L bq1 bk1^T  (fp32 out)
__global__ __launch_bounds__(256) void gemm_S(
    const unsigned short* __restrict__ P,
    const unsigned short* __restrict__ Wk1b,
    const float* __restrict__ bias5,
    const float* __restrict__ u, const float* __restrict__ w,
    float* __restrict__ Sf)
{
  __shared__ unsigned short smem[32768];
  const int bid = blockIdx.x;
  const int wgid = (bid & 7) * 16 + (bid >> 3);    // 128 blocks
  const int z = wgid >> 4;
  const int mtile = (wgid >> 2) & 3, ntile = wgid & 3;
  const int m0 = mtile * 128, n0 = ntile * 128;
  const int K = 512;
  const unsigned short* Ae = P + (size_t)z * 262144;
  const unsigned short* Be = Wk1b + (size_t)n0 * 512;

  GEMM_PRE();
  GEMM_KLOOP2(8, Be);

  #pragma unroll
  for (int j = 0; j < 4; j++){
    int cd = n0 + wn*64 + j*16 + l15;
    float bkv = bias5[2048 + cd];
    float wv  = w[z*512 + cd] + 4096.0f * bkv;
    #pragma unroll
    for (int i = 0; i < 4; i++){
      int r = m0 + wm*64 + i*16 + kg*4;
      #pragma unroll
      for (int q = 0; q < 4; q++){
        int rr = r + q;
        float uq  = u[z*512 + rr];
        float bqv = bias5[1536 + rr];
        Sf[(size_t)z * 262144 + (size_t)rr * 512 + cd] =
            acc[i][j][q] + uq * bkv + bqv * wv;
      }
    }
  }
}

// ===========================================================================
// result GEMM (128² 2-phase, 1024 blocks, 2/CU):
// y = xs + gamma*Z[l]*(Q @ midT'^T) in-place + BN stats.
// ===========================================================================
__global__ __launch_bounds__(256, 2) void gemm_res2(
    const unsigned short* __restrict__ A,        // Qb [32768][512]
    const unsigned short* __restrict__ Bt,       // midT' [8][512][512]
    const float* __restrict__ Zp,                // [32768]
    unsigned short* __restrict__ outh,           // xs bf16, in-place -> y
    const float* __restrict__ gamma_p,
    float* __restrict__ bnS, float* __restrict__ bnQ)
{
  __shared__ unsigned short smem[32768];
  __shared__ float zbuf[128];
  const int bid = blockIdx.x;
  const int wgid = (bid & 7) * 128 + (bid >> 3);   // 1024 % 8 == 0: bijective
  const int mtile = wgid >> 2;                     // 0..255
  const int ntile = wgid & 3;
  const int m0 = mtile * 128;
  const int nc0 = ntile * 128;
  const int K = 512;
  const unsigned short* Ae = A;
  const unsigned short* Be =
      Bt + (size_t)(mtile >> 5) * 262144 + (size_t)nc0 * 512;

  GEMM_PRE();
  GEMM_KLOOP2(8, Be);

  const float g = gamma_p[0];
  if (tid < 128) zbuf[tid] = Zp[m0 + tid];
  __syncthreads();
  // stage 1: g*Z*acc -> LDS bf16 (stride 136, conflict-free)
  #pragma unroll
  for (int j = 0; j < 4; j++){
    const int cl = wn*64 + j*16 + l15;
    #pragma unroll
    for (int i = 0; i < 4; i++){
      const int rb = wm*64 + i*16 + kg*4;
      #pragma unroll
      for (int q = 0; q < 4; q++){
        const int rl = rb + q;
        smem[rl*136 + cl] = f2bf(g * zbuf[rl] * acc[i][j][q]);
      }
    }
  }
  __syncthreads();
  // stage 2: coalesced RMW over the 128x128 tile + per-thread col partials
  float sc[8] = {0.f,0.f,0.f,0.f,0.f,0.f,0.f,0.f};
  float sq[8] = {0.f,0.f,0.f,0.f,0.f,0.f,0.f,0.f};
  const int c0 = (tid & 15) * 8;
  #pragma unroll
  for (int rep = 0; rep < 8; rep++){
    const int rl = rep*16 + (tid >> 4);
    bf16x8 ga = *(const bf16x8*)&smem[rl*136 + c0];
    size_t gidx = (size_t)(m0 + rl) * 512 + nc0 + c0;
    bf16x8 xv = *(const bf16x8*)(outh + gidx);
    bf16x8 yv;
    #pragma unroll
    for (int j = 0; j < 8; j++){
      float y = bf2f((unsigned short)xv[j]) + bf2f((unsigned short)ga[j]);
      yv[j] = (short)f2bf(y);
      sc[j] += y; sq[j] += y * y;
    }
    *(bf16x8*)(outh + gidx) = yv;
  }
  __syncthreads();
  // stage 3: reduce col partials across the 16 row-groups, then atomics
  float* red = (float*)(void*)smem;     // [16][128] sc ; +2048: [16][128] sq
  const int tg = tid >> 4;
  f32x4 s0 = {sc[0],sc[1],sc[2],sc[3]}, s1 = {sc[4],sc[5],sc[6],sc[7]};
  f32x4 q0 = {sq[0],sq[1],sq[2],sq[3]}, q1 = {sq[4],sq[5],sq[6],sq[7]};
  *(f32x4*)&red[tg*128 + c0]        = s0;  *(f32x4*)&red[tg*128 + c0 + 4]        = s1;
  *(f32x4*)&red[2048 + tg*128 + c0] = q0;  *(f32x4*)&red[2048 + tg*128 + c0 + 4] = q1;
  __syncthreads();
  if (tid < 128){
    float ss = 0.f, qq = 0.f;
    #pragma unroll
    for (int gg = 0; gg < 16; gg++){
      ss += red[gg*128 + tid];
      qq += red[2048 + gg*128 + tid];
    }
    atomicAdd(&bnS[nc0 + tid], ss);
    atomicAdd(&bnQ[nc0 + tid], qq);
  }
}

// ---------------------------------------------------------------------------
// finalize: y[b][l][c] bf16 -> out[b][c][l] fp32, BN affine + relu
__global__ __launch_bounds__(256) void k_bn_finalize(
    const unsigned short* __restrict__ y, const float* __restrict__ bnS,
    const float* __restrict__ bnQ, const float* __restrict__ bnw,
    const float* __restrict__ bnb, float* __restrict__ out)
{
  __shared__ float tile[64][65];
  __shared__ float scale_s[64], shift_s[64];
  const int lt = blockIdx.x, ct = blockIdx.y, b = blockIdx.z;
  const int t = threadIdx.x;
  if (t < 64){
    int c = ct*64 + t;
    float s = bnS[c], q = bnQ[c];
    float mean = s * (1.0f / 32768.0f);
    float var  = q * (1.0f / 32768.0f) - mean * mean;
    float inv  = rsqrtf(var + 1e-5f);
    float scv  = bnw[c] * inv;
    scale_s[t] = scv;
    shift_s[t] = bnb[c] - mean * scv;
  }
  const int rr = t >> 3, c8 = (t & 7) * 8;
  #pragma unroll
  for (int pass = 0; pass < 2; pass++){
    int l = rr + pass * 32;
    bf16x8 v = *(const bf16x8*)(y + ((size_t)b * 4096 + lt*64 + l) * 512 + ct*64 + c8);
    #pragma unroll
    for (int s = 0; s < 8; s++) tile[l][c8+s] = bf2f((unsigned short)v[s]);
  }
  __syncthreads();
  #pragma unroll
  for (int pass = 0; pass < 2; pass++){
    int c = rr + pass * 32;
    float scv = scale_s[c], sh = shift_s[c];
    f32x4 o0, o1;
    #pragma unroll
    for (int s = 0; s < 4; s++){
      float v = tile[c8+s][c] * scv + sh;     o0[s] = v > 0.f ? v : 0.f;
      float w = tile[c8+4+s][c] * scv + sh;   o1[s] = w > 0.f ? w : 0.f;
    }
    float* dp = out + ((size_t)b * 512 + ct*64 + c) * 4096 + lt*64 + c8;
    *(f32x4*)dp = o0;
    *(f32x4*)(dp + 4) = o1;
  }
}

// ---------------------------------------------------------------------------
extern "C" void kernel_launch(void* const* d_in, const int* in_sizes, int n_in,
                              void* d_out, int out_size, void* d_ws, size_t ws_size,
                              hipStream_t stream)
{
  const float* x    = (const float*)d_in[0];
  const float* pos  = (const float*)d_in[1];
  const float* Wq   = (const float*)d_in[2];
  const float* bq   = (const float*)d_in[3];
  const float* Wk   = (const float*)d_in[4];
  const float* bk   = (const float*)d_in[5];
  const float* Wv   = (const float*)d_in[6];
  const float* bv   = (const float*)d_in[7];
  const float* Wq1  = (const float*)d_in[8];
  const float* bq1  = (const float*)d_in[9];
  const float* Wk1  = (const float*)d_in[10];
  const float* bk1  = (const float*)d_in[11];
  const float* gam  = (const float*)d_in[12];
  const float* bnw  = (const float*)d_in[13];
  const float* bnb  = (const float*)d_in[14];
  float* out = (float*)d_out;
  char* ws = (char*)d_ws;

  const size_t MB = 1ull << 20;
  const size_t OFF_XSB  = 0;                  // 32MB xs_bf -> y in-place
  const size_t OFF_QB   = 32*MB;              // 32MB Q
  const size_t OFF_XST  = 64*MB;              // 32MB xs^T [8][512][4096]
  const size_t OFF_GSTK = 96*MB;              // 8MB  Gstack bf16 [8][512][1024]
  const size_t OFF_PBF  = 104*MB;             // 4MB  P bf16
  const size_t OFF_SF   = 108*MB;             // 8MB  S fp32
  const size_t OFF_MIDT = 120*MB;             // 4MB  midT' bf16 (diag-scaled)
  const size_t OFF_WBF  = 124*MB;             // 2.5MB
  const size_t OFF_WQ2  = 127*MB;             // 1MB  Wq1 duplicated [512][1024]
  const size_t OFF_B5   = 128*MB + 512*1024;  // 10KB
  const size_t OFF_UV   = 129*MB;             // 16KB u
  const size_t OFF_WV   = OFF_UV + 16384;     // 16KB w
  const size_t OFF_Z    = OFF_WV + 16384;     // 128KB Z fp32
  const size_t OFF_DIAG = 130*MB;             // zeroed region start
  const size_t OFF_KSUM = OFF_DIAG + 16384;
  const size_t OFF_BNS  = OFF_KSUM + 16384;
  const size_t OFF_BNQ  = OFF_BNS + 2048;
  const size_t OFF_SV   = OFF_BNQ + 2048;
  const size_t ZERO_LEN = 16384 + 16384 + 2048 + 2048 + 16384;
  const size_t WS_NEED  = OFF_SV + 16384;
  if (ws_size < WS_NEED) return;

  unsigned short* xsb  = (unsigned short*)(ws + OFF_XSB);
  unsigned short* Qb   = (unsigned short*)(ws + OFF_QB);
  unsigned short* xsT  = (unsigned short*)(ws + OFF_XST);
  unsigned short* Gstk = (unsigned short*)(ws + OFF_GSTK);
  unsigned short* Pbf  = (unsigned short*)(ws + OFF_PBF);
  float*          Sf   = (float*)(ws + OFF_SF);
  unsigned short* midT = (unsigned short*)(ws + OFF_MIDT);
  unsigned short* wbf  = (unsigned short*)(ws + OFF_WBF);
  unsigned short* wq1x2= (unsigned short*)(ws + OFF_WQ2);
  float* bias5 = (float*)(ws + OFF_B5);
  float* uvec = (float*)(ws + OFF_UV);
  float* wvec = (float*)(ws + OFF_WV);
  float* Zp   = (float*)(ws + OFF_Z);
  float* diag = (float*)(ws + OFF_DIAG);
  float* ksum = (float*)(ws + OFF_KSUM);
  float* bnS  = (float*)(ws + OFF_BNS);
  float* bnQ  = (float*)(ws + OFF_BNQ);
  float* svec = (float*)(ws + OFF_SV);

  hipMemsetAsync(ws + OFF_DIAG, 0, ZERO_LEN, stream);

  // merged prep + build (build blocks dispatch first; prep fills behind)
  k_prep_build<<<dim3(6154), 256, 0, stream>>>(
      x, pos, Wq, Wk, Wv, Wq1, Wk1, bq, bk, bv, bq1, bk1,
      xsb, xsT, svec, wbf, bias5, wq1x2);

  // MEGA: proj (Q + chained-KV) + G-syrk + uw co-scheduled in one launch
  k_mega<<<dim3(2320), 256, 0, stream>>>(xsb, xsT, wbf, bias5, svec,
                                         Qb, Gstk, diag, ksum, uvec, wvec);

  // gemm_P co-launched with Z row-normalizer (independent paths)
  k_pz<<<dim3(8320), 256, 0, stream>>>(wq1x2, Gstk, Pbf, Qb, ksum, Zp);

  // S = Wq1 G Wk1^T + rank-1 corrections
  gemm_S<<<dim3(128), 256, 0, stream>>>(Pbf, wbf + 4*262144, bias5, uvec, wvec, Sf);

  // softmax + diag-scale + transpose, one pass
  k_softmax_t2<<<dim3(64, 8), 256, 0, stream>>>(Sf, diag, midT);

  // result GEMM (128², 2/CU) + residual + BN-stat epilogue (y in-place)
  gemm_res2<<<dim3(1024), 256, 0, stream>>>(Qb, midT, Zp, xsb, gam, bnS, bnQ);

  k_bn_finalize<<<dim3(64, 8, 8), 256, 0, stream>>>(xsb, bnS, bnQ, bnw, bnb, out);
}

// Round 12
// 209.778 us; speedup vs baseline: 1.0505x; 1.0279x over previous
//
#include <hip/hip_runtime.h>
#include <stdint.h>

typedef float f32x4 __attribute__((ext_vector_type(4)));
typedef short bf16x8 __attribute__((ext_vector_type(8)));

__device__ __forceinline__ float bf2f(unsigned short h){
  union { unsigned int u; float f; } v; v.u = ((unsigned int)h) << 16; return v.f;
}
__device__ __forceinline__ unsigned short f2bf(float f){
  union { float f; unsigned int u; } v; v.f = f;
  return (unsigned short)((v.u + 0x7fffu + ((v.u >> 16) & 1u)) >> 16);
}

typedef __attribute__((address_space(1))) const unsigned int ga_u32;
typedef __attribute__((address_space(3))) unsigned int ls_u32;
__device__ __forceinline__ void async_load16(const void* g, void* l){
  __builtin_amdgcn_global_load_lds((ga_u32*)g, (ls_u32*)l, 16, 0, 0);
}

#define CFENCE() asm volatile("" ::: "memory")

// ===========================================================================
// merged prep + build_xs:
//  bid 0..511    : build xs/xsT/svec (lt = bid&63, ct = bid>>6)  [heavy, first]
//  bid 512..5631 : weights fp32->bf16 (5 x 512x512)
//  bid 5632..5641: biases packed
//  bid 5642..6153: wq1x2 dup from fp32 Wq1
// ===========================================================================
__global__ __launch_bounds__(256) void k_prep_build(
    const float* __restrict__ x, const float* __restrict__ pos,
    const float* __restrict__ w0, const float* __restrict__ w1,
    const float* __restrict__ w2, const float* __restrict__ w3,
    const float* __restrict__ w4,
    const float* __restrict__ b0, const float* __restrict__ b1,
    const float* __restrict__ b2, const float* __restrict__ b3,
    const float* __restrict__ b4,
    unsigned short* __restrict__ xsb, unsigned short* __restrict__ xsT,
    float* __restrict__ svec,
    unsigned short* __restrict__ wbf, float* __restrict__ bias5,
    unsigned short* __restrict__ wq1x2)
{
  __shared__ float tile[64][65];
  __shared__ unsigned short tile2[64][72];
  __shared__ float sred[256];
  const int bid = blockIdx.x;
  const int t = threadIdx.x;

  if (bid >= 512){
    if (bid < 5632){
      int wbid = bid - 512;
      int slot = wbid >> 10;
      int i = (wbid & 1023) * 256 + t;
      const float* w = (slot == 0) ? w0 : (slot == 1) ? w1 :
                       (slot == 2) ? w2 : (slot == 3) ? w3 : w4;
      wbf[(size_t)slot * 262144 + i] = f2bf(w[i]);
    } else if (bid < 5642){
      int i = (bid - 5632) * 256 + t;   // 0..2559
      int s = i >> 9, r = i & 511;
      const float* b = (s == 0) ? b0 : (s == 1) ? b1 : (s == 2) ? b2 :
                       (s == 3) ? b3 : b4;
      bias5[i] = b[r];
    } else {
      int e = bid - 5642;               // 0..511
      #pragma unroll
      for (int rep = 0; rep < 2; rep++){
        int idx = rep*256 + t;
        unsigned short v = f2bf(w3[e*512 + idx]);   // w3 == Wq1 fp32
        wq1x2[(size_t)e*1024 + idx] = v;
        wq1x2[(size_t)e*1024 + 512 + idx] = v;
      }
    }
    return;
  }

  // ---------------- build path ----------------
  const int lt = bid & 63, ct = bid >> 6;
  const int rr = t >> 3, c8 = (t & 7) * 8;
  float pr[16];
  #pragma unroll
  for (int pass = 0; pass < 2; pass++){
    int gl = lt*64 + rr + pass*32;
    f32x4 p0 = *(const f32x4*)(pos + (size_t)gl * 512 + ct*64 + c8);
    f32x4 p1 = *(const f32x4*)(pos + (size_t)gl * 512 + ct*64 + c8 + 4);
    #pragma unroll
    for (int s = 0; s < 4; s++){ pr[pass*8+s] = p0[s]; pr[pass*8+4+s] = p1[s]; }
  }
  for (int b = 0; b < 8; b++){
    #pragma unroll
    for (int pass = 0; pass < 2; pass++){
      int r = rr + pass * 32;
      const float* src = x + ((size_t)b * 512 + ct*64 + r) * 4096 + lt*64 + c8;
      f32x4 v0 = *(const f32x4*)src;
      f32x4 v1 = *(const f32x4*)(src + 4);
      #pragma unroll
      for (int s = 0; s < 4; s++){ tile[r][c8+s] = v0[s]; tile[r][c8+4+s] = v1[s]; }
    }
    __syncthreads();
    #pragma unroll
    for (int pass = 0; pass < 2; pass++){
      int ll = rr + pass * 32;
      int gl = lt*64 + ll;
      bf16x8 hv;
      #pragma unroll
      for (int s = 0; s < 8; s++){
        unsigned short h = f2bf(tile[c8+s][ll] + pr[pass*8+s]);
        hv[s] = (short)h;
        tile2[c8+s][ll] = h;
      }
      *(bf16x8*)(xsb + ((size_t)b * 4096 + gl) * 512 + ct*64 + c8) = hv;
    }
    __syncthreads();
    #pragma unroll
    for (int rep = 0; rep < 2; rep++){
      int c = rep*32 + (t >> 3);
      int l0 = (t & 7) * 8;
      bf16x8 v = *(const bf16x8*)&tile2[c][l0];
      *(bf16x8*)(xsT + ((size_t)b * 512 + ct*64 + c) * 4096 + lt*64 + l0) = v;
    }
    {
      const int c = t & 63, lq = t >> 6;
      float s_ = 0.f;
      #pragma unroll
      for (int j = 0; j < 16; j++) s_ += bf2f(tile2[c][lq*16 + j]);
      sred[t] = s_;
      __syncthreads();
      if (t < 64){
        float ss = sred[t] + sred[t+64] + sred[t+128] + sred[t+192];
        atomicAdd(&svec[b*512 + ct*64 + t], ss);
      }
    }
    __syncthreads();
  }
}

// ===========================================================================
// merged softmax + diag-scale + transpose:
// midT[z][d][c] = softmax_d(S[z][c][:])[d] * diag[z][c]
// ===========================================================================
__global__ __launch_bounds__(256) void k_softmax_t2(
    const float* __restrict__ Sf, const float* __restrict__ diag,
    unsigned short* __restrict__ midT)
{
  __shared__ unsigned short tr[8][520];
  const int rc = blockIdx.x, z = blockIdx.y;
  const int t = threadIdx.x;
  const int w = t >> 6, lane = t & 63;
  #pragma unroll
  for (int rr = 0; rr < 2; rr++){
    int cl = w*2 + rr;                     // 0..7
    int c = rc*8 + cl;
    const float* p = Sf + ((size_t)z*512 + c)*512 + lane*8;
    f32x4 v0 = *(const f32x4*)p, v1 = *(const f32x4*)(p + 4);
    float mx = v0[0];
    #pragma unroll
    for (int s = 1; s < 4; s++) mx = fmaxf(mx, v0[s]);
    #pragma unroll
    for (int s = 0; s < 4; s++) mx = fmaxf(mx, v1[s]);
    #pragma unroll
    for (int m = 1; m < 64; m <<= 1) mx = fmaxf(mx, __shfl_xor(mx, m));
    float e[8]; float sum = 0.f;
    #pragma unroll
    for (int s = 0; s < 4; s++){ e[s]   = __expf(v0[s] - mx); sum += e[s]; }
    #pragma unroll
    for (int s = 0; s < 4; s++){ e[4+s] = __expf(v1[s] - mx); sum += e[4+s]; }
    #pragma unroll
    for (int m = 1; m < 64; m <<= 1) sum += __shfl_xor(sum, m);
    float scl = diag[z*512 + c] / sum;
    #pragma unroll
    for (int s = 0; s < 8; s++) tr[cl][lane*8 + s] = f2bf(e[s] * scl);
  }
  __syncthreads();
  #pragma unroll
  for (int rep = 0; rep < 2; rep++){
    int d = rep*256 + t;
    bf16x8 hv;
    #pragma unroll
    for (int s = 0; s < 8; s++) hv[s] = (short)tr[s][d];
    *(bf16x8*)(midT + ((size_t)z*512 + d)*512 + rc*8) = hv;
  }
}

// ===========================================================================
// 128x128-tile 2-phase GEMM machinery (64KB LDS -> 2 blocks/CU).
// ===========================================================================
#define GEMM_PRE()                                                            \
  const int tid = threadIdx.x;                                                \
  const int lane = tid & 63;                                                  \
  const int wave = tid >> 6;                                                  \
  const int wm = wave >> 1, wn = wave & 1;                                    \
  size_t aoff[4], boff[4]; int ldsq[4];                                       \
  _Pragma("unroll")                                                           \
  for (int i = 0; i < 4; i++){                                                \
    int qq = i*4 + wave;                                                      \
    int ch = qq*64 + lane;                                                    \
    int m  = ch >> 3, p = ch & 7;                                             \
    int lc = p ^ (m & 7);                                                     \
    aoff[i] = (size_t)(m0 + m) * K + lc*8;                                    \
    boff[i] = (size_t)m * K + lc*8;                                           \
    ldsq[i] = qq * 1024;                                                      \
  }                                                                           \
  f32x4 acc[4][4];                                                            \
  const f32x4 vzero = {0.f,0.f,0.f,0.f};                                      \
  _Pragma("unroll")                                                           \
  for (int i = 0; i < 4; i++)                                                 \
    _Pragma("unroll")                                                         \
    for (int j = 0; j < 4; j++) acc[i][j] = vzero;                            \
  int arow[4], brow[4];                                                       \
  _Pragma("unroll")                                                           \
  for (int f = 0; f < 4; f++){                                                \
    arow[f] = (wm*64 + f*16 + (lane & 15)) * 64;                              \
    brow[f] = (wn*64 + f*16 + (lane & 15)) * 64;                              \
  }                                                                           \
  const int kg = lane >> 4;                                                   \
  const int l7 = lane & 7;                                                    \
  const int l15 = lane & 15;

#define GEMM_STAGE2(buf, kt, BB)                                              \
  _Pragma("unroll")                                                           \
  for (int i = 0; i < 4; i++){                                                \
    async_load16(Ae + aoff[i] + (kt)*64, (char*)&smem[(buf)*8192] + ldsq[i]); \
    async_load16((BB) + boff[i] + (kt)*64, (char*)&smem[16384 + (buf)*8192] + ldsq[i]); \
  }

#define GEMM_COMPUTE2(buf, ACC)                                               \
  _Pragma("unroll")                                                           \
  for (int ks = 0; ks < 2; ks++){                                             \
    bf16x8 a[4], b[4];                                                        \
    const int pa = (ks*4 + kg) ^ l7;                                          \
    _Pragma("unroll")                                                         \
    for (int f = 0; f < 4; f++){                                              \
      a[f] = *(const bf16x8*)&smem[(buf)*8192 + arow[f] + pa*8];              \
      b[f] = *(const bf16x8*)&smem[16384 + (buf)*8192 + brow[f] + pa*8];      \
    }                                                                         \
    _Pragma("unroll")                                                         \
    for (int i = 0; i < 4; i++)                                               \
      _Pragma("unroll")                                                       \
      for (int j = 0; j < 4; j++)                                             \
        (ACC)[i][j] = __builtin_amdgcn_mfma_f32_16x16x32_bf16(a[i], b[j], (ACC)[i][j], 0, 0, 0); \
  }

#define GEMM_KLOOP2(nkt, BB)                                                  \
  GEMM_STAGE2(0, 0, BB);                                                      \
  __syncthreads();                                                            \
  { int cur = 0;                                                              \
    for (int kt = 0; kt < (nkt); kt++){                                       \
      if (kt + 1 < (nkt)) { GEMM_STAGE2(cur ^ 1, kt + 1, BB); }               \
      GEMM_COMPUTE2(cur, acc);                                                \
      __syncthreads();                                                        \
      cur ^= 1;                                                               \
    } }

// ===========================================================================
// MEGA kernel: proj (Q + chained KV) + symmetric-G-syrk + uw, one launch.
// grid = 2224 = 8 XCD-chunks x 278 (20 G + 256 proj + 2 uw).
// G computes only upper-triangle tile pairs (i<=j); mirrors written transposed.
// ===========================================================================
__constant__ const int g_pi[10] = {0,0,0,0,1,1,1,2,2,3};
__constant__ const int g_pj[10] = {0,1,2,3,1,2,3,2,3,3};

__global__ __launch_bounds__(256, 2) void k_mega(
    const unsigned short* __restrict__ A,      // xsb
    const unsigned short* __restrict__ xsT,
    const unsigned short* __restrict__ W,
    const float* __restrict__ bias5,
    const float* __restrict__ svec,
    unsigned short* __restrict__ Qb,
    unsigned short* __restrict__ Gstk,
    float* __restrict__ diag, float* __restrict__ ksum,
    float* __restrict__ uvec, float* __restrict__ wvec)
{
  __shared__ unsigned short smem[32768];   // 64KB
  const int bid = blockIdx.x;
  const int xcd = bid & 7, local = bid >> 3;   // local 0..277

  if (local < 20){
    // ---------------- symmetric G-syrk path ----------------
    const int z = xcd;                            // one z per XCD
    const int part = local / 10;
    const int pair = local % 10;
    const int ti = g_pi[pair], tj = g_pj[pair];
    const int m0 = ti * 128, n0 = tj * 128;
    const int K = 4096;
    const unsigned short* Ae = xsT + (size_t)z * 2097152 + part * 2048;
    const unsigned short* Be = Ae + (size_t)n0 * 4096;

    GEMM_PRE();
    GEMM_KLOOP2(32, Be);

    #pragma unroll
    for (int j = 0; j < 4; j++){
      const int cl = wn*64 + j*16 + l15;
      #pragma unroll
      for (int i = 0; i < 4; i++){
        const int rb = wm*64 + i*16 + kg*4;
        #pragma unroll
        for (int q = 0; q < 4; q++)
          smem[(rb + q)*136 + cl] = f2bf(acc[i][j][q]);
      }
    }
    __syncthreads();
    #pragma unroll
    for (int rep = 0; rep < 8; rep++){
      const int rl = rep*16 + (tid >> 4);
      const int c0 = (tid & 15) * 8;
      bf16x8 v = *(const bf16x8*)&smem[rl*136 + c0];
      *(bf16x8*)(Gstk + (size_t)z*524288 + (size_t)(m0 + rl)*1024 + part*512 + n0 + c0) = v;
    }
    if (ti != tj){
      // mirror: Gstk[z][n0+c][part*512+m0+...] = tile^T (read cols from LDS)
      #pragma unroll
      for (int rep = 0; rep < 8; rep++){
        const int c   = rep*16 + (tid >> 4);    // original col
        const int rlg = tid & 15;
        const int rl0 = rlg * 8;
        bf16x8 hv;
        #pragma unroll
        for (int s = 0; s < 8; s++){
          int jj = (s + rlg) & 7;
          hv[jj] = (short)smem[(rl0 + jj)*136 + c];
        }
        *(bf16x8*)(Gstk + (size_t)z*524288 + (size_t)(n0 + c)*1024 + part*512 + m0 + rl0) = hv;
      }
    }
    return;
  }

  if (local >= 276){
    // ---------------- uw path ----------------
    const int uwid = xcd*2 + (local - 276);      // 0..15
    const int sel = uwid & 1, b = uwid >> 1;
    const int t = threadIdx.x;
    float* sv = (float*)(void*)smem;             // 2KB
    sv[t] = svec[b*512 + t]; sv[t+256] = svec[b*512 + t + 256];
    __syncthreads();
    const unsigned short* Wp = W + (size_t)(3 + sel) * 262144;
    float* o = sel ? wvec : uvec;
    #pragma unroll
    for (int rep = 0; rep < 2; rep++){
      int e = rep*256 + t;
      const unsigned short* row = Wp + (size_t)e * 512;
      float acc_ = 0.f;
      for (int ch = 0; ch < 64; ch++){
        bf16x8 v = *(const bf16x8*)(row + ch*8);
        #pragma unroll
        for (int j = 0; j < 8; j++) acc_ += bf2f((unsigned short)v[j]) * sv[ch*8+j];
      }
      o[b*512 + e] = acc_;
    }
    return;
  }

  // ---------------- proj path ----------------
  const int pw = xcd*256 + (local - 20);         // 0..2047
  const int mtile = pw >> 3;                     // 0..255
  const int unit  = pw & 7;
  const int m0 = mtile * 128;
  const int K = 512;
  const unsigned short* Ae = A;

  int mode, cb;
  const unsigned short* BeK; const unsigned short* BeV = W;
  if (unit < 4){ mode = 0; cb = unit*128;     BeK = W + (size_t)cb * 512; }
  else         { mode = 1; cb = (unit-4)*128; BeK = W + 262144 + (size_t)cb * 512;
                                              BeV = W + 524288 + (size_t)cb * 512; }

  GEMM_PRE();

  if (mode == 1){
    const int bz = mtile >> 5;
    GEMM_STAGE2(0, 0, BeK);
    __syncthreads();
    int cur = 0;
    for (int kt = 0; kt < 8; kt++){
      if (kt < 7) { GEMM_STAGE2(cur ^ 1, kt + 1, BeK); }
      else        { GEMM_STAGE2(cur ^ 1, 0, BeV); }
      GEMM_COMPUTE2(cur, acc);
      __syncthreads();
      cur ^= 1;
    }
    GEMM_STAGE2(cur ^ 1, 1, BeV);
    unsigned int kpk[4][4][2];
    #pragma unroll
    for (int j = 0; j < 4; j++){
      const int cj = cb + wn*64 + j*16 + l15;
      const float bb = bias5[512 + cj];
      float ks_ = 0.f;
      #pragma unroll
      for (int i = 0; i < 4; i++){
        #pragma unroll
        for (int h = 0; h < 2; h++){
          float v0 = acc[i][j][2*h]   + bb; v0 = v0 > 0.f ? v0 : 0.f;
          float v1 = acc[i][j][2*h+1] + bb; v1 = v1 > 0.f ? v1 : 0.f;
          unsigned short h0 = f2bf(v0), h1 = f2bf(v1);
          kpk[i][j][h] = (unsigned)h0 | ((unsigned)h1 << 16);
          ks_ += bf2f(h0) + bf2f(h1);
        }
        acc[i][j] = vzero;
      }
      ks_ += __shfl_xor(ks_, 16);
      ks_ += __shfl_xor(ks_, 32);
      if (lane < 16) atomicAdd(&ksum[bz*512 + cj], ks_);
    }
    for (int kt = 0; kt < 8; kt++){
      if (kt >= 1 && kt < 7) { GEMM_STAGE2(cur ^ 1, kt + 1, BeV); }
      GEMM_COMPUTE2(cur, acc);
      __syncthreads();
      cur ^= 1;
    }
    #pragma unroll
    for (int j = 0; j < 4; j++){
      const int cj = cb + wn*64 + j*16 + l15;
      const float bb = bias5[1024 + cj];
      float dv = 0.f;
      #pragma unroll
      for (int i = 0; i < 4; i++){
        #pragma unroll
        for (int h = 0; h < 2; h++){
          float v0 = bf2f(f2bf(acc[i][j][2*h]   + bb));
          float v1 = bf2f(f2bf(acc[i][j][2*h+1] + bb));
          dv += bf2f((unsigned short)(kpk[i][j][h] & 0xffffu)) * v0
              + bf2f((unsigned short)(kpk[i][j][h] >> 16))     * v1;
        }
      }
      dv += __shfl_xor(dv, 16);
      dv += __shfl_xor(dv, 32);
      if (lane < 16) atomicAdd(&diag[bz*512 + cj], dv);
    }
    return;
  }

  GEMM_KLOOP2(8, BeK);

  #pragma unroll
  for (int j = 0; j < 4; j++){
    const int cl = wn*64 + j*16 + l15;
    const float bb = bias5[cb + cl];
    #pragma unroll
    for (int i = 0; i < 4; i++){
      const int rb = wm*64 + i*16 + kg*4;
      #pragma unroll
      for (int q = 0; q < 4; q++){
        float v = acc[i][j][q] + bb; v = v > 0.f ? v : 0.f;
        smem[(rb + q)*136 + cl] = f2bf(v);
      }
    }
  }
  __syncthreads();
  #pragma unroll
  for (int rep = 0; rep < 8; rep++){
    const int rl = rep*16 + (tid >> 4);
    const int c0 = (tid & 15) * 8;
    bf16x8 v = *(const bf16x8*)&smem[rl*136 + c0];
    *(bf16x8*)(Qb + (size_t)(m0 + rl) * 512 + cb + c0) = v;
  }
}

// ===========================================================================
// k_pz: gemm_P (bids 0..127) co-launched with k_z (bids 128..8319).
// ===========================================================================
__global__ __launch_bounds__(256) void k_pz(
    const unsigned short* __restrict__ Wq1x2,
    const unsigned short* __restrict__ Gstk,
    unsigned short* __restrict__ P,
    const unsigned short* __restrict__ Qb,
    const float* __restrict__ ksum,
    float* __restrict__ Z)
{
  __shared__ unsigned short smem[32768];
  const int bid = blockIdx.x;

  if (bid >= 128){
    // ---------------- Z path ----------------
    const int row = (bid - 128) * 4 + ((int)threadIdx.x >> 6);
    const int lane = threadIdx.x & 63;
    const int b = row >> 12;
    bf16x8 q = *(const bf16x8*)(Qb + (size_t)row * 512 + lane * 8);
    f32x4 k0 = *(const f32x4*)(ksum + b*512 + lane*8);
    f32x4 k1 = *(const f32x4*)(ksum + b*512 + lane*8 + 4);
    float den = 0.f;
    #pragma unroll
    for (int s = 0; s < 4; s++) den += bf2f((unsigned short)q[s])   * (k0[s] + 1e-6f);
    #pragma unroll
    for (int s = 0; s < 4; s++) den += bf2f((unsigned short)q[4+s]) * (k1[s] + 1e-6f);
    #pragma unroll
    for (int m = 1; m < 64; m <<= 1) den += __shfl_xor(den, m);
    if (lane == 0) Z[row] = 1.0f / den;
    return;
  }

  // ---------------- P path: P[z] = Wq1 @ (G0+G1), K=1024 ----------------
  const int wgid = (bid & 7) * 16 + (bid >> 3);    // bijective on 0..127
  const int z = wgid >> 4;
  const int mtile = (wgid >> 2) & 3, ntile = wgid & 3;
  const int m0 = mtile * 128, n0 = ntile * 128;
  const int K = 1024;
  const unsigned short* Ae = Wq1x2;
  const unsigned short* Be = Gstk + (size_t)z * 524288 + (size_t)n0 * 1024;

  GEMM_PRE();
  GEMM_KLOOP2(16, Be);

  #pragma unroll
  for (int j = 0; j < 4; j++){
    const int cl = wn*64 + j*16 + l15;
    #pragma unroll
    for (int i = 0; i < 4; i++){
      const int rb = wm*64 + i*16 + kg*4;
      #pragma unroll
      for (int q = 0; q < 4; q++)
        smem[(rb + q)*136 + cl] = f2bf(acc[i][j][q]);
    }
  }
  __syncthreads();
  #pragma unroll
  for (int rep = 0; rep < 8; rep++){
    const int rl = rep*16 + (tid >> 4);
    const int c0 = (tid & 15) * 8;
    bf16x8 v = *(const bf16x8*)&smem[rl*136 + c0];
    *(bf16x8*)(P + (size_t)z * 262144 + (size_t)(m0 + rl) * 512 + n0 + c0) = v;
  }
}

// ---------------------------------------------------------------------------
// S[z] = P[z] @ Wk1^T + u bk1^T + bq1 w^T + L bq1 bk1^T  (fp32 out)
__global__ __launch_bounds__(256) void gemm_S(
    const unsigned short* __restrict__ P,
    const unsigned short* __restrict__ Wk1b,
    const float* __restrict__ bias5,
    const float* __restrict__ u, const float* __restrict__ w,
    float* __restrict__ Sf)
{
  __shared__ unsigned short smem[32768];
  const int bid = blockIdx.x;
  const int wgid = (bid & 7) * 16 + (bid >> 3);    // 128 blocks
  const int z = wgid >> 4;
  const int mtile = (wgid >> 2) & 3, ntile = wgid & 3;
  const int m0 = mtile * 128, n0 = ntile * 128;
  const int K = 512;
  const unsigned short* Ae = P + (size_t)z * 262144;
  const unsigned short* Be = Wk1b + (size_t)n0 * 512;

  GEMM_PRE();
  GEMM_KLOOP2(8, Be);

  #pragma unroll
  for (int j = 0; j < 4; j++){
    int cd = n0 + wn*64 + j*16 + l15;
    float bkv = bias5[2048 + cd];
    float wv  = w[z*512 + cd] + 4096.0f * bkv;
    #pragma unroll
    for (int i = 0; i < 4; i++){
      int r = m0 + wm*64 + i*16 + kg*4;
      #pragma unroll
      for (int q = 0; q < 4; q++){
        int rr = r + q;
        float uq  = u[z*512 + rr];
        float bqv = bias5[1536 + rr];
        Sf[(size_t)z * 262144 + (size_t)rr * 512 + cd] =
            acc[i][j][q] + uq * bkv + bqv * wv;
      }
    }
  }
}

// ===========================================================================
// result GEMM (128² 2-phase, 1024 blocks, 2/CU):
// y = xs + gamma*Z[l]*(Q @ midT'^T) in-place + BN stats.
// ===========================================================================
__global__ __launch_bounds__(256, 2) void gemm_res2(
    const unsigned short* __restrict__ A,        // Qb [32768][512]
    const unsigned short* __restrict__ Bt,       // midT' [8][512][512]
    const float* __restrict__ Zp,                // [32768]
    unsigned short* __restrict__ outh,           // xs bf16, in-place -> y
    const float* __restrict__ gamma_p,
    float* __restrict__ bnS, float* __restrict__ bnQ)
{
  __shared__ unsigned short smem[32768];
  __shared__ float zbuf[128];
  const int bid = blockIdx.x;
  const int wgid = (bid & 7) * 128 + (bid >> 3);   // 1024 % 8 == 0: bijective
  const int mtile = wgid >> 2;                     // 0..255
  const int ntile = wgid & 3;
  const int m0 = mtile * 128;
  const int nc0 = ntile * 128;
  const int K = 512;
  const unsigned short* Ae = A;
  const unsigned short* Be =
      Bt + (size_t)(mtile >> 5) * 262144 + (size_t)nc0 * 512;

  GEMM_PRE();
  GEMM_KLOOP2(8, Be);

  const float g = gamma_p[0];
  if (tid < 128) zbuf[tid] = Zp[m0 + tid];
  __syncthreads();
  // stage 1: g*Z*acc -> LDS bf16 (stride 136, conflict-free)
  #pragma unroll
  for (int j = 0; j < 4; j++){
    const int cl = wn*64 + j*16 + l15;
    #pragma unroll
    for (int i = 0; i < 4; i++){
      const int rb = wm*64 + i*16 + kg*4;
      #pragma unroll
      for (int q = 0; q < 4; q++){
        const int rl = rb + q;
        smem[rl*136 + cl] = f2bf(g * zbuf[rl] * acc[i][j][q]);
      }
    }
  }
  __syncthreads();
  // stage 2: coalesced RMW over the 128x128 tile + per-thread col partials
  float sc[8] = {0.f,0.f,0.f,0.f,0.f,0.f,0.f,0.f};
  float sq[8] = {0.f,0.f,0.f,0.f,0.f,0.f,0.f,0.f};
  const int c0 = (tid & 15) * 8;
  #pragma unroll
  for (int rep = 0; rep < 8; rep++){
    const int rl = rep*16 + (tid >> 4);
    bf16x8 ga = *(const bf16x8*)&smem[rl*136 + c0];
    size_t gidx = (size_t)(m0 + rl) * 512 + nc0 + c0;
    bf16x8 xv = *(const bf16x8*)(outh + gidx);
    bf16x8 yv;
    #pragma unroll
    for (int j = 0; j < 8; j++){
      float y = bf2f((unsigned short)xv[j]) + bf2f((unsigned short)ga[j]);
      yv[j] = (short)f2bf(y);
      sc[j] += y; sq[j] += y * y;
    }
    *(bf16x8*)(outh + gidx) = yv;
  }
  __syncthreads();
  // stage 3: reduce col partials across the 16 row-groups, then atomics
  float* red = (float*)(void*)smem;     // [16][128] sc ; +2048: [16][128] sq
  const int tg = tid >> 4;
  f32x4 s0 = {sc[0],sc[1],sc[2],sc[3]}, s1 = {sc[4],sc[5],sc[6],sc[7]};
  f32x4 q0 = {sq[0],sq[1],sq[2],sq[3]}, q1 = {sq[4],sq[5],sq[6],sq[7]};
  *(f32x4*)&red[tg*128 + c0]        = s0;  *(f32x4*)&red[tg*128 + c0 + 4]        = s1;
  *(f32x4*)&red[2048 + tg*128 + c0] = q0;  *(f32x4*)&red[2048 + tg*128 + c0 + 4] = q1;
  __syncthreads();
  if (tid < 128){
    float ss = 0.f, qq = 0.f;
    #pragma unroll
    for (int gg = 0; gg < 16; gg++){
      ss += red[gg*128 + tid];
      qq += red[2048 + gg*128 + tid];
    }
    atomicAdd(&bnS[nc0 + tid], ss);
    atomicAdd(&bnQ[nc0 + tid], qq);
  }
}

// ---------------------------------------------------------------------------
// finalize: y[b][l][c] bf16 -> out[b][c][l] fp32, BN affine + relu
__global__ __launch_bounds__(256) void k_bn_finalize(
    const unsigned short* __restrict__ y, const float* __restrict__ bnS,
    const float* __restrict__ bnQ, const float* __restrict__ bnw,
    const float* __restrict__ bnb, float* __restrict__ out)
{
  __shared__ float tile[64][65];
  __shared__ float scale_s[64], shift_s[64];
  const int lt = blockIdx.x, ct = blockIdx.y, b = blockIdx.z;
  const int t = threadIdx.x;
  if (t < 64){
    int c = ct*64 + t;
    float s = bnS[c], q = bnQ[c];
    float mean = s * (1.0f / 32768.0f);
    float var  = q * (1.0f / 32768.0f) - mean * mean;
    float inv  = rsqrtf(var + 1e-5f);
    float scv  = bnw[c] * inv;
    scale_s[t] = scv;
    shift_s[t] = bnb[c] - mean * scv;
  }
  const int rr = t >> 3, c8 = (t & 7) * 8;
  #pragma unroll
  for (int pass = 0; pass < 2; pass++){
    int l = rr + pass * 32;
    bf16x8 v = *(const bf16x8*)(y + ((size_t)b * 4096 + lt*64 + l) * 512 + ct*64 + c8);
    #pragma unroll
    for (int s = 0; s < 8; s++) tile[l][c8+s] = bf2f((unsigned short)v[s]);
  }
  __syncthreads();
  #pragma unroll
  for (int pass = 0; pass < 2; pass++){
    int c = rr + pass * 32;
    float scv = scale_s[c], sh = shift_s[c];
    f32x4 o0, o1;
    #pragma unroll
    for (int s = 0; s < 4; s++){
      float v = tile[c8+s][c] * scv + sh;     o0[s] = v > 0.f ? v : 0.f;
      float w = tile[c8+4+s][c] * scv + sh;   o1[s] = w > 0.f ? w : 0.f;
    }
    float* dp = out + ((size_t)b * 512 + ct*64 + c) * 4096 + lt*64 + c8;
    *(f32x4*)dp = o0;
    *(f32x4*)(dp + 4) = o1;
  }
}

// ---------------------------------------------------------------------------
extern "C" void kernel_launch(void* const* d_in, const int* in_sizes, int n_in,
                              void* d_out, int out_size, void* d_ws, size_t ws_size,
                              hipStream_t stream)
{
  const float* x    = (const float*)d_in[0];
  const float* pos  = (const float*)d_in[1];
  const float* Wq   = (const float*)d_in[2];
  const float* bq   = (const float*)d_in[3];
  const float* Wk   = (const float*)d_in[4];
  const float* bk   = (const float*)d_in[5];
  const float* Wv   = (const float*)d_in[6];
  const float* bv   = (const float*)d_in[7];
  const float* Wq1  = (const float*)d_in[8];
  const float* bq1  = (const float*)d_in[9];
  const float* Wk1  = (const float*)d_in[10];
  const float* bk1  = (const float*)d_in[11];
  const float* gam  = (const float*)d_in[12];
  const float* bnw  = (const float*)d_in[13];
  const float* bnb  = (const float*)d_in[14];
  float* out = (float*)d_out;
  char* ws = (char*)d_ws;

  const size_t MB = 1ull << 20;
  const size_t OFF_XSB  = 0;                  // 32MB xs_bf -> y in-place
  const size_t OFF_QB   = 32*MB;              // 32MB Q
  const size_t OFF_XST  = 64*MB;              // 32MB xs^T [8][512][4096]
  const size_t OFF_GSTK = 96*MB;              // 8MB  Gstack bf16 [8][512][1024]
  const size_t OFF_PBF  = 104*MB;             // 4MB  P bf16
  const size_t OFF_SF   = 108*MB;             // 8MB  S fp32
  const size_t OFF_MIDT = 120*MB;             // 4MB  midT' bf16 (diag-scaled)
  const size_t OFF_WBF  = 124*MB;             // 2.5MB
  const size_t OFF_WQ2  = 127*MB;             // 1MB  Wq1 duplicated [512][1024]
  const size_t OFF_B5   = 128*MB + 512*1024;  // 10KB
  const size_t OFF_UV   = 129*MB;             // 16KB u
  const size_t OFF_WV   = OFF_UV + 16384;     // 16KB w
  const size_t OFF_Z    = OFF_WV + 16384;     // 128KB Z fp32
  const size_t OFF_DIAG = 130*MB;             // zeroed region start
  const size_t OFF_KSUM = OFF_DIAG + 16384;
  const size_t OFF_BNS  = OFF_KSUM + 16384;
  const size_t OFF_BNQ  = OFF_BNS + 2048;
  const size_t OFF_SV   = OFF_BNQ + 2048;
  const size_t ZERO_LEN = 16384 + 16384 + 2048 + 2048 + 16384;
  const size_t WS_NEED  = OFF_SV + 16384;
  if (ws_size < WS_NEED) return;

  unsigned short* xsb  = (unsigned short*)(ws + OFF_XSB);
  unsigned short* Qb   = (unsigned short*)(ws + OFF_QB);
  unsigned short* xsT  = (unsigned short*)(ws + OFF_XST);
  unsigned short* Gstk = (unsigned short*)(ws + OFF_GSTK);
  unsigned short* Pbf  = (unsigned short*)(ws + OFF_PBF);
  float*          Sf   = (float*)(ws + OFF_SF);
  unsigned short* midT = (unsigned short*)(ws + OFF_MIDT);
  unsigned short* wbf  = (unsigned short*)(ws + OFF_WBF);
  unsigned short* wq1x2= (unsigned short*)(ws + OFF_WQ2);
  float* bias5 = (float*)(ws + OFF_B5);
  float* uvec = (float*)(ws + OFF_UV);
  float* wvec = (float*)(ws + OFF_WV);
  float* Zp   = (float*)(ws + OFF_Z);
  float* diag = (float*)(ws + OFF_DIAG);
  float* ksum = (float*)(ws + OFF_KSUM);
  float* bnS  = (float*)(ws + OFF_BNS);
  float* bnQ  = (float*)(ws + OFF_BNQ);
  float* svec = (float*)(ws + OFF_SV);

  hipMemsetAsync(ws + OFF_DIAG, 0, ZERO_LEN, stream);

  // merged prep + build (build blocks dispatch first; prep fills behind)
  k_prep_build<<<dim3(6154), 256, 0, stream>>>(
      x, pos, Wq, Wk, Wv, Wq1, Wk1, bq, bk, bv, bq1, bk1,
      xsb, xsT, svec, wbf, bias5, wq1x2);

  // MEGA: proj (Q + chained-KV) + symmetric-G + uw co-scheduled in one launch
  k_mega<<<dim3(2224), 256, 0, stream>>>(xsb, xsT, wbf, bias5, svec,
                                         Qb, Gstk, diag, ksum, uvec, wvec);

  // gemm_P co-launched with Z row-normalizer (independent paths)
  k_pz<<<dim3(8320), 256, 0, stream>>>(wq1x2, Gstk, Pbf, Qb, ksum, Zp);

  // S = Wq1 G Wk1^T + rank-1 corrections
  gemm_S<<<dim3(128), 256, 0, stream>>>(Pbf, wbf + 4*262144, bias5, uvec, wvec, Sf);

  // softmax + diag-scale + transpose, one pass
  k_softmax_t2<<<dim3(64, 8), 256, 0, stream>>>(Sf, diag, midT);

  // result GEMM (128², 2/CU) + residual + BN-stat epilogue (y in-place)
  gemm_res2<<<dim3(1024), 256, 0, stream>>>(Qb, midT, Zp, xsb, gam, bnS, bnQ);

  k_bn_finalize<<<dim3(64, 8, 8), 256, 0, stream>>>(xsb, bnS, bnQ, bnw, bnb, out);
}